// Round 1
// baseline (3801.327 us; speedup 1.0000x reference)
//
#include <hip/hip_runtime.h>
#include <hip/hip_bf16.h>
#include <cstdint>

// Problem constants
constexpr int KD   = 1024;   // d_model
constexpr int NH   = 16;     // heads
constexpr int HDIM = 64;     // head dim
constexpr int DFF  = 4096;   // ffn dim
constexpr int NB   = 4;      // batch
constexpr int SEQ  = 1024;   // seq len
constexpr int ROWS = NB * SEQ;        // 4096 token rows
constexpr long long AROWS = (long long)NB * NH * SEQ;  // 65536 attention rows

typedef signed char i8;

__device__ __forceinline__ void atomicMaxF(float* addr, float v) {
    // valid for non-negative floats (bit pattern monotone); scal is zeroed first
    atomicMax((unsigned int*)addr, __float_as_uint(v));
}

// ---------------- absmax over f32 tensor ----------------
__global__ __launch_bounds__(256) void absmax_f32(const float* __restrict__ x, long long n, float* __restrict__ out) {
    float m = 0.f;
    for (long long i = (long long)blockIdx.x * blockDim.x + threadIdx.x; i < n;
         i += (long long)gridDim.x * blockDim.x)
        m = fmaxf(m, fabsf(x[i]));
    __shared__ float red[256];
    red[threadIdx.x] = m; __syncthreads();
    for (int s = 128; s > 0; s >>= 1) {
        if (threadIdx.x < s) red[threadIdx.x] = fmaxf(red[threadIdx.x], red[threadIdx.x + s]);
        __syncthreads();
    }
    if (threadIdx.x == 0) atomicMaxF(out, red[0]);
}

// ---------------- quantize f32 -> int8 codes ----------------
__global__ __launch_bounds__(256) void quant_f32_i8(const float* __restrict__ x, long long n,
                                                    const float* __restrict__ mp, i8* __restrict__ q) {
    float s = fmaxf(mp[0] * (1.f / 127.f), 1e-8f);
    for (long long i = (long long)blockIdx.x * blockDim.x + threadIdx.x; i < n;
         i += (long long)gridDim.x * blockDim.x) {
        float v = rintf(x[i] / s);
        v = fminf(fmaxf(v, -128.f), 127.f);
        q[i] = (i8)(int)v;
    }
}

// ---------------- generic int8 GEMM  C = sa*sb*(A @ B[^T]) (+bias) ----------------
// A: Mg x Kg (row-major, lda). TRANS_B: B is Ng x Kg; else B is Kg x Ng.
// MODE 0: write f32 y and atomicMax |y|; MODE 1: max only; MODE 2: write int8 quantized by scal[iout].
template<bool TRANS_B, int MODE>
__global__ __launch_bounds__(256) void gemm_q8(
    const i8* __restrict__ A, int lda, long long sAb, long long sAh,
    const i8* __restrict__ Bm, int ldb, long long sBb, long long sBh,
    void* __restrict__ Cout, int ldc, long long sCb, long long sCh,
    int Mg, int Ng, int Kg, int Hdiv,
    const float* __restrict__ scal, int ia, int ib, int iout,
    const float* __restrict__ bias, float* __restrict__ maxout)
{
    int z = blockIdx.z;
    int bb = z / Hdiv, hh = z % Hdiv;
    A  += bb * sAb + hh * sAh;
    Bm += bb * sBb + hh * sBh;
    long long coff = (long long)bb * sCb + (long long)hh * sCh;

    __shared__ float As[16][65];
    __shared__ float Bs[16][65];
    __shared__ float red[256];

    int tid = threadIdx.x;
    int tx = tid & 15, ty = tid >> 4;
    int m0 = blockIdx.y * 64, n0 = blockIdx.x * 64;
    float acc[4][4] = {};

    for (int k0 = 0; k0 < Kg; k0 += 16) {
        #pragma unroll
        for (int i = 0; i < 4; i++) {
            int idx = tid + i * 256;
            int r = idx >> 4, c = idx & 15;
            As[c][r] = (float)A[(long long)(m0 + r) * lda + k0 + c];
        }
        if (TRANS_B) {
            #pragma unroll
            for (int i = 0; i < 4; i++) {
                int idx = tid + i * 256;
                int r = idx >> 4, c = idx & 15;
                Bs[c][r] = (float)Bm[(long long)(n0 + r) * ldb + k0 + c];
            }
        } else {
            #pragma unroll
            for (int i = 0; i < 4; i++) {
                int idx = tid + i * 256;
                int r = idx >> 6, c = idx & 63;
                Bs[r][c] = (float)Bm[(long long)(k0 + r) * ldb + n0 + c];
            }
        }
        __syncthreads();
        #pragma unroll
        for (int kk = 0; kk < 16; kk++) {
            float a[4], b[4];
            #pragma unroll
            for (int i = 0; i < 4; i++) a[i] = As[kk][ty * 4 + i];
            #pragma unroll
            for (int j = 0; j < 4; j++) b[j] = Bs[kk][tx * 4 + j];
            #pragma unroll
            for (int i = 0; i < 4; i++)
                #pragma unroll
                for (int j = 0; j < 4; j++)
                    acc[i][j] += a[i] * b[j];
        }
        __syncthreads();
    }

    float sa = fmaxf(scal[ia] * (1.f / 127.f), 1e-8f);
    float sb = fmaxf(scal[ib] * (1.f / 127.f), 1e-8f);
    float ab = sa * sb;
    float so = 1.f;
    if (MODE == 2) so = fmaxf(scal[iout] * (1.f / 127.f), 1e-8f);

    float lmax = 0.f;
    #pragma unroll
    for (int i = 0; i < 4; i++) {
        int row = m0 + ty * 4 + i;
        #pragma unroll
        for (int j = 0; j < 4; j++) {
            int col = n0 + tx * 4 + j;
            float y = ab * acc[i][j];
            if (bias) y += bias[col];
            if (MODE == 0)
                ((float*)Cout)[coff + (long long)row * ldc + col] = y;
            if (MODE == 2) {
                float qv = fminf(fmaxf(rintf(y / so), -128.f), 127.f);
                ((i8*)Cout)[coff + (long long)row * ldc + col] = (i8)(int)qv;
            }
            lmax = fmaxf(lmax, fabsf(y));
        }
    }
    if (MODE <= 1) {
        red[tid] = lmax; __syncthreads();
        for (int s2 = 128; s2 > 0; s2 >>= 1) {
            if (tid < s2) red[tid] = fmaxf(red[tid], red[tid + s2]);
            __syncthreads();
        }
        if (tid == 0) atomicMaxF(maxout, red[0]);
    }
}

// ---------------- softmax over quantized scores ----------------
// scores value = qS * scale_s / 8 ; row = one (b,h,i)
__global__ __launch_bounds__(256) void softmax_stats(const i8* __restrict__ qS, const float* __restrict__ scal, int is,
                                                     float* __restrict__ rowM, float* __restrict__ rowZ, float* __restrict__ pmax) {
    long long row = blockIdx.x;
    const i8* p = qS + row * SEQ;
    float ss = fmaxf(scal[is] * (1.f / 127.f), 1e-8f);
    float c = ss * 0.125f;
    int tid = threadIdx.x;
    float v[4];
    #pragma unroll
    for (int i = 0; i < 4; i++) v[i] = (float)p[tid + i * 256];
    float m = fmaxf(fmaxf(v[0], v[1]), fmaxf(v[2], v[3]));
    __shared__ float red[256];
    red[tid] = m; __syncthreads();
    for (int s = 128; s > 0; s >>= 1) {
        if (tid < s) red[tid] = fmaxf(red[tid], red[tid + s]);
        __syncthreads();
    }
    m = red[0]; __syncthreads();
    float z = 0.f;
    #pragma unroll
    for (int i = 0; i < 4; i++) z += expf(c * (v[i] - m));
    red[tid] = z; __syncthreads();
    for (int s = 128; s > 0; s >>= 1) {
        if (tid < s) red[tid] += red[tid + s];
        __syncthreads();
    }
    if (tid == 0) {
        rowM[row] = m;
        rowZ[row] = red[0];
        atomicMaxF(pmax, 1.f / red[0]);  // max prob of this row is exactly 1/Z
    }
}

__global__ __launch_bounds__(256) void softmax_apply(i8* __restrict__ qS, const float* __restrict__ scal, int is, int ip,
                                                     const float* __restrict__ rowM, const float* __restrict__ rowZ) {
    long long row = blockIdx.x;
    i8* p = qS + row * SEQ;
    float ss = fmaxf(scal[is] * (1.f / 127.f), 1e-8f);
    float c = ss * 0.125f;
    float sp = fmaxf(scal[ip] * (1.f / 127.f), 1e-8f);
    float m = rowM[row];
    float Z = rowZ[row];
    int tid = threadIdx.x;
    #pragma unroll
    for (int i = 0; i < 4; i++) {
        int j = tid + i * 256;
        float pr = expf(c * ((float)p[j] - m)) / Z;
        float qv = fminf(fmaxf(rintf(pr / sp), -128.f), 127.f);
        p[j] = (i8)(int)qv;
    }
}

// ---------------- residual + LayerNorm ----------------
template<bool WMAX>
__global__ __launch_bounds__(256) void ln_res(const float* __restrict__ base, const i8* __restrict__ qadd,
                                              const float* __restrict__ scal, int isc,
                                              const float* __restrict__ g, const float* __restrict__ bb,
                                              float* __restrict__ out, float* __restrict__ xmax) {
    long long row = blockIdx.x;
    int tid = threadIdx.x;
    float s = fmaxf(scal[isc] * (1.f / 127.f), 1e-8f);
    float v[4];
    float sum = 0.f, sq = 0.f;
    #pragma unroll
    for (int i = 0; i < 4; i++) {
        int j = tid + i * 256;
        float x = base[row * KD + j] + (float)qadd[row * KD + j] * s;
        v[i] = x; sum += x; sq += x * x;
    }
    __shared__ float r1[256], r2[256];
    r1[tid] = sum; r2[tid] = sq; __syncthreads();
    for (int st = 128; st > 0; st >>= 1) {
        if (tid < st) { r1[tid] += r1[tid + st]; r2[tid] += r2[tid + st]; }
        __syncthreads();
    }
    float mu  = r1[0] * (1.f / 1024.f);
    float var = r2[0] * (1.f / 1024.f) - mu * mu;
    float inv = 1.f / sqrtf(var + 1e-5f);
    float lmax = 0.f;
    #pragma unroll
    for (int i = 0; i < 4; i++) {
        int j = tid + i * 256;
        float xn = (v[i] - mu) * inv * g[j] + bb[j];
        out[row * KD + j] = xn;
        lmax = fmaxf(lmax, fabsf(xn));
    }
    if (WMAX) {
        __syncthreads();
        r1[tid] = lmax; __syncthreads();
        for (int st = 128; st > 0; st >>= 1) {
            if (tid < st) r1[tid] = fmaxf(r1[tid], r1[tid + st]);
            __syncthreads();
        }
        if (tid == 0) atomicMaxF(xmax, r1[0]);
    }
}

// ---------------- FFN mid: quantize y, relu, track max of relu(fq(y)) ----------------
__global__ __launch_bounds__(256) void relu_quant_a(const float* __restrict__ y, long long n,
                                                    const float* __restrict__ scal, int ih,
                                                    i8* __restrict__ qh, float* __restrict__ rmax) {
    float s = fmaxf(scal[ih] * (1.f / 127.f), 1e-8f);
    float lmax = 0.f;
    for (long long i = (long long)blockIdx.x * blockDim.x + threadIdx.x; i < n;
         i += (long long)gridDim.x * blockDim.x) {
        float qv = fminf(fmaxf(rintf(y[i] / s), -128.f), 127.f);
        qh[i] = (i8)(int)qv;
        float val = qv > 0.f ? qv * s : 0.f;
        lmax = fmaxf(lmax, val);
    }
    __shared__ float red[256];
    red[threadIdx.x] = lmax; __syncthreads();
    for (int st = 128; st > 0; st >>= 1) {
        if (threadIdx.x < st) red[threadIdx.x] = fmaxf(red[threadIdx.x], red[threadIdx.x + st]);
        __syncthreads();
    }
    if (threadIdx.x == 0) atomicMaxF(rmax, red[0]);
}

__global__ __launch_bounds__(256) void relu_quant_b(i8* __restrict__ qh, long long n,
                                                    const float* __restrict__ scal, int ih, int ir) {
    float s  = fmaxf(scal[ih] * (1.f / 127.f), 1e-8f);
    float sr = fmaxf(scal[ir] * (1.f / 127.f), 1e-8f);
    for (long long i = (long long)blockIdx.x * blockDim.x + threadIdx.x; i < n;
         i += (long long)gridDim.x * blockDim.x) {
        int qv = qh[i];
        float val = qv > 0 ? (float)qv * s : 0.f;
        float q2 = fminf(fmaxf(rintf(val / sr), -128.f), 127.f);
        qh[i] = (i8)(int)q2;
    }
}

// ---------------- launch ----------------
extern "C" void kernel_launch(void* const* d_in, const int* in_sizes, int n_in,
                              void* d_out, int out_size, void* d_ws, size_t ws_size,
                              hipStream_t stream) {
    const float* src = (const float*)d_in[0];
    const float* wq  = (const float*)d_in[1];
    const float* wk  = (const float*)d_in[2];
    const float* wv  = (const float*)d_in[3];
    const float* wo  = (const float*)d_in[4];
    const float* w1  = (const float*)d_in[5];
    const float* b1  = (const float*)d_in[6];
    const float* w2  = (const float*)d_in[7];
    const float* b2  = (const float*)d_in[8];
    const float* g1  = (const float*)d_in[9];
    const float* bb1 = (const float*)d_in[10];
    const float* g2  = (const float*)d_in[11];
    const float* bb2 = (const float*)d_in[12];
    float* out = (float*)d_out;

    char* ws = (char*)d_ws;
    size_t off = 0;
    auto alloc = [&](size_t bytes) -> char* {
        char* p = ws + off;
        off = (off + bytes + 255) & ~(size_t)255;
        return p;
    };
    float* scal = (float*)alloc(256);
    float* rowM = (float*)alloc(AROWS * 4);
    float* rowZ = (float*)alloc(AROWS * 4);
    i8* qsrc = (i8*)alloc((size_t)ROWS * KD);
    i8* qwq  = (i8*)alloc((size_t)KD * KD);
    i8* qwk  = (i8*)alloc((size_t)KD * KD);
    i8* qwv  = (i8*)alloc((size_t)KD * KD);
    i8* qwo  = (i8*)alloc((size_t)KD * KD);
    i8* qw1  = (i8*)alloc((size_t)DFF * KD);
    i8* qw2  = (i8*)alloc((size_t)KD * DFF);
    i8* qQ   = (i8*)alloc((size_t)ROWS * KD);
    i8* qK   = (i8*)alloc((size_t)ROWS * KD);
    i8* qV   = (i8*)alloc((size_t)ROWS * KD);
    i8* qA   = (i8*)alloc((size_t)ROWS * KD);
    i8* qAo  = (i8*)alloc((size_t)ROWS * KD);
    i8* qX   = (i8*)alloc((size_t)ROWS * KD);
    i8* qFF  = (i8*)alloc((size_t)ROWS * KD);
    i8* qH   = (i8*)alloc((size_t)ROWS * DFF);
    i8* qS   = (i8*)alloc((size_t)NB * NH * SEQ * SEQ);
    float* xbuf = (float*)alloc((size_t)ROWS * KD * 4);
    float* ybuf = (float*)alloc((size_t)ROWS * DFF * 4);
    (void)ws_size; (void)in_sizes; (void)n_in; (void)out_size;

    hipMemsetAsync(scal, 0, 256, stream);

    // 1. input absmaxes
    absmax_f32<<<1024, 256, 0, stream>>>(src, (long long)ROWS * KD, &scal[0]);
    absmax_f32<<<256, 256, 0, stream>>>(wq, (long long)KD * KD, &scal[1]);
    absmax_f32<<<256, 256, 0, stream>>>(wk, (long long)KD * KD, &scal[2]);
    absmax_f32<<<256, 256, 0, stream>>>(wv, (long long)KD * KD, &scal[3]);
    absmax_f32<<<256, 256, 0, stream>>>(wo, (long long)KD * KD, &scal[4]);
    absmax_f32<<<1024, 256, 0, stream>>>(w1, (long long)DFF * KD, &scal[5]);
    absmax_f32<<<1024, 256, 0, stream>>>(w2, (long long)KD * DFF, &scal[6]);

    // 2. quantize inputs
    quant_f32_i8<<<1024, 256, 0, stream>>>(src, (long long)ROWS * KD, &scal[0], qsrc);
    quant_f32_i8<<<256, 256, 0, stream>>>(wq, (long long)KD * KD, &scal[1], qwq);
    quant_f32_i8<<<256, 256, 0, stream>>>(wk, (long long)KD * KD, &scal[2], qwk);
    quant_f32_i8<<<256, 256, 0, stream>>>(wv, (long long)KD * KD, &scal[3], qwv);
    quant_f32_i8<<<256, 256, 0, stream>>>(wo, (long long)KD * KD, &scal[4], qwo);
    quant_f32_i8<<<1024, 256, 0, stream>>>(w1, (long long)DFF * KD, &scal[5], qw1);
    quant_f32_i8<<<1024, 256, 0, stream>>>(w2, (long long)KD * DFF, &scal[6], qw2);

    // 3. Q/K/V projections
    dim3 gProj(KD / 64, ROWS / 64, 1);
    gemm_q8<true, 0><<<gProj, 256, 0, stream>>>(qsrc, KD, 0, 0, qwq, KD, 0, 0, ybuf, KD, 0, 0,
                                                ROWS, KD, KD, 1, scal, 0, 1, -1, nullptr, &scal[7]);
    quant_f32_i8<<<1024, 256, 0, stream>>>(ybuf, (long long)ROWS * KD, &scal[7], qQ);
    gemm_q8<true, 0><<<gProj, 256, 0, stream>>>(qsrc, KD, 0, 0, qwk, KD, 0, 0, ybuf, KD, 0, 0,
                                                ROWS, KD, KD, 1, scal, 0, 2, -1, nullptr, &scal[8]);
    quant_f32_i8<<<1024, 256, 0, stream>>>(ybuf, (long long)ROWS * KD, &scal[8], qK);
    gemm_q8<true, 0><<<gProj, 256, 0, stream>>>(qsrc, KD, 0, 0, qwv, KD, 0, 0, ybuf, KD, 0, 0,
                                                ROWS, KD, KD, 1, scal, 0, 3, -1, nullptr, &scal[9]);
    quant_f32_i8<<<1024, 256, 0, stream>>>(ybuf, (long long)ROWS * KD, &scal[9], qV);

    // 4. scores = q @ k^T per (b,h) : pass1 max-only, pass2 quantize to int8
    dim3 gSc(SEQ / 64, SEQ / 64, NB * NH);
    const long long sQb = (long long)SEQ * KD;   // per-batch stride in qQ/qK/qV
    const long long sSb = (long long)NH * SEQ * SEQ;
    const long long sSh = (long long)SEQ * SEQ;
    gemm_q8<true, 1><<<gSc, 256, 0, stream>>>(qQ, KD, sQb, HDIM, qK, KD, sQb, HDIM,
                                              nullptr, SEQ, sSb, sSh,
                                              SEQ, SEQ, HDIM, NH, scal, 7, 8, -1, nullptr, &scal[10]);
    gemm_q8<true, 2><<<gSc, 256, 0, stream>>>(qQ, KD, sQb, HDIM, qK, KD, sQb, HDIM,
                                              qS, SEQ, sSb, sSh,
                                              SEQ, SEQ, HDIM, NH, scal, 7, 8, 10, nullptr, nullptr);

    // 5. softmax (stats, then quantize probs in place)
    softmax_stats<<<(unsigned)AROWS, 256, 0, stream>>>(qS, scal, 10, rowM, rowZ, &scal[11]);
    softmax_apply<<<(unsigned)AROWS, 256, 0, stream>>>(qS, scal, 10, 11, rowM, rowZ);

    // 6. attn = probs @ v per (b,h) -> ybuf in [b,n,h*64+d] layout
    dim3 gPV(HDIM / 64, SEQ / 64, NB * NH);
    gemm_q8<false, 0><<<gPV, 256, 0, stream>>>(qS, SEQ, sSb, sSh, qV, KD, sQb, HDIM,
                                               ybuf, KD, sQb, HDIM,
                                               SEQ, HDIM, SEQ, NH, scal, 11, 9, -1, nullptr, &scal[12]);
    quant_f32_i8<<<1024, 256, 0, stream>>>(ybuf, (long long)ROWS * KD, &scal[12], qA);

    // 7. output projection
    gemm_q8<true, 0><<<gProj, 256, 0, stream>>>(qA, KD, 0, 0, qwo, KD, 0, 0, ybuf, KD, 0, 0,
                                                ROWS, KD, KD, 1, scal, 12, 4, -1, nullptr, &scal[13]);
    quant_f32_i8<<<1024, 256, 0, stream>>>(ybuf, (long long)ROWS * KD, &scal[13], qAo);

    // 8. residual + LN1 -> xbuf (track max for quantization)
    ln_res<true><<<ROWS, 256, 0, stream>>>(src, qAo, scal, 13, g1, bb1, xbuf, &scal[14]);
    quant_f32_i8<<<1024, 256, 0, stream>>>(xbuf, (long long)ROWS * KD, &scal[14], qX);

    // 9. FFN1 (+b1), quantize, relu, requantize
    dim3 gF1(DFF / 64, ROWS / 64, 1);
    gemm_q8<true, 0><<<gF1, 256, 0, stream>>>(qX, KD, 0, 0, qw1, KD, 0, 0, ybuf, DFF, 0, 0,
                                              ROWS, DFF, KD, 1, scal, 14, 5, -1, b1, &scal[15]);
    relu_quant_a<<<2048, 256, 0, stream>>>(ybuf, (long long)ROWS * DFF, scal, 15, qH, &scal[16]);
    relu_quant_b<<<2048, 256, 0, stream>>>(qH, (long long)ROWS * DFF, scal, 15, 16);

    // 10. FFN2 (+b2), quantize
    dim3 gF2(KD / 64, ROWS / 64, 1);
    gemm_q8<true, 0><<<gF2, 256, 0, stream>>>(qH, DFF, 0, 0, qw2, DFF, 0, 0, ybuf, KD, 0, 0,
                                              ROWS, KD, DFF, 1, scal, 16, 6, -1, b2, &scal[17]);
    quant_f32_i8<<<1024, 256, 0, stream>>>(ybuf, (long long)ROWS * KD, &scal[17], qFF);

    // 11. residual + LN2 -> out
    ln_res<false><<<ROWS, 256, 0, stream>>>(xbuf, qFF, scal, 17, g2, bb2, out, nullptr);
}

// Round 2
// 1255.371 us; speedup vs baseline: 3.0281x; 3.0281x over previous
//
#include <hip/hip_runtime.h>
#include <cstdint>

// Problem constants
constexpr int KD   = 1024;
constexpr int NH   = 16;
constexpr int HDIM = 64;
constexpr int DFF  = 4096;
constexpr int NBATCH = 4;
constexpr int SEQ  = 1024;
constexpr int ROWS = NBATCH * SEQ;                       // 4096
constexpr long long AROWS = (long long)NBATCH * NH * SEQ; // 65536

typedef signed char i8;
typedef unsigned short u16;
typedef __attribute__((ext_vector_type(8))) short short8;
typedef __attribute__((ext_vector_type(4))) float f32x4;

__device__ __forceinline__ void atomicMaxF(float* a, float v) {
    atomicMax((unsigned int*)a, __float_as_uint(v));   // valid: values >= 0, buffer zeroed
}
// int8 code values are exact in bf16: low 16 bits of their f32 pattern are zero.
__device__ __forceinline__ float c2f(u16 u) { return __uint_as_float(((unsigned)u) << 16); }
__device__ __forceinline__ u16   f2c(float f) { return (u16)(__float_as_uint(f) >> 16); }
__device__ __forceinline__ float qclamp(float x) { return fminf(fmaxf(x, -128.f), 127.f); }

#define GLDS16(gp, lp) __builtin_amdgcn_global_load_lds( \
    (const __attribute__((address_space(1))) void*)(gp), \
    (__attribute__((address_space(3))) void*)(lp), 16, 0, 0)

// ---------------- absmax over f32 tensor (float4 + shuffle reduce) ----------------
__global__ __launch_bounds__(256) void absmax_f32(const float4* __restrict__ x, long long n4,
                                                  float* __restrict__ out) {
    float m = 0.f;
    for (long long i = (long long)blockIdx.x * blockDim.x + threadIdx.x; i < n4;
         i += (long long)gridDim.x * blockDim.x) {
        float4 v = x[i];
        m = fmaxf(m, fmaxf(fmaxf(fabsf(v.x), fabsf(v.y)), fmaxf(fabsf(v.z), fabsf(v.w))));
    }
    #pragma unroll
    for (int off = 32; off; off >>= 1) m = fmaxf(m, __shfl_xor(m, off, 64));
    __shared__ float sm[4];
    int lane = threadIdx.x & 63, wid = threadIdx.x >> 6;
    if (lane == 0) sm[wid] = m;
    __syncthreads();
    if (threadIdx.x == 0) atomicMaxF(out, fmaxf(fmaxf(sm[0], sm[1]), fmaxf(sm[2], sm[3])));
}

// ---------------- quantize f32 -> bf16 code bits (exact grid: n/1024 blocks) ----------------
__global__ __launch_bounds__(256) void quant_to_bf16(const float4* __restrict__ x,
                                                     const float* __restrict__ mp,
                                                     ushort4* __restrict__ q) {
    long long i = (long long)blockIdx.x * 256 + threadIdx.x;
    float s = fmaxf(mp[0] * (1.f / 127.f), 1e-8f);
    float4 v = x[i];
    ushort4 o;
    o.x = f2c(qclamp(rintf(v.x / s)));
    o.y = f2c(qclamp(rintf(v.y / s)));
    o.z = f2c(qclamp(rintf(v.z / s)));
    o.w = f2c(qclamp(rintf(v.w / s)));
    q[i] = o;
}

// ---------------- MFMA GEMM on bf16 codes: C = sa*sb*(A @ B^T) (+bias) ----------------
// A: M x K (lda), B: N x K (ldb)  [B given transposed, i.e. weight layout / K matrix]
// 128x128 tile, BK=64, 4 waves (2x2 of 64x64), global_load_lds staging (m97 structure).
// MODE 0: write f32 + track max; 1: max only; 2: write int8 quantized by scal[iout].
template<int MODE>
__global__ __launch_bounds__(256) void gemm_mfma(
    const u16* __restrict__ A, int lda, long long sAb, long long sAh,
    const u16* __restrict__ B, int ldb, long long sBb, long long sBh,
    void* __restrict__ Cout, int ldc, long long sCb, long long sCh,
    int Kg, int Hdiv,
    const float* __restrict__ scal, int ia, int ib, int iout,
    const float* __restrict__ bias, float* __restrict__ maxout)
{
    __shared__ u16 As[128][64];
    __shared__ u16 Bs[128][64];
    __shared__ float wred[4];

    int z = blockIdx.z, zb = z / Hdiv, zh = z % Hdiv;
    A += (long long)zb * sAb + (long long)zh * sAh;
    B += (long long)zb * sBb + (long long)zh * sBh;
    long long coff = (long long)zb * sCb + (long long)zh * sCh;

    int tid = threadIdx.x, lane = tid & 63, wid = tid >> 6;
    int wr = wid >> 1, wc = wid & 1;
    int m0 = blockIdx.y * 128, n0 = blockIdx.x * 128;

    f32x4 acc[4][4];
    #pragma unroll
    for (int m = 0; m < 4; ++m)
        #pragma unroll
        for (int n = 0; n < 4; ++n) acc[m][n] = (f32x4)0.0f;

    int srow = lane >> 3;            // 0..7 row within 8-row slab
    int scol = (lane & 7) * 8;       // bf16 element col (16B chunk)

    for (int k0 = 0; k0 < Kg; k0 += 64) {
        #pragma unroll
        for (int i = 0; i < 4; ++i) {
            int r = wid * 32 + i * 8 + srow;
            GLDS16(A + (long long)(m0 + r) * lda + k0 + scol, &As[wid * 32 + i * 8][0]);
        }
        #pragma unroll
        for (int i = 0; i < 4; ++i) {
            int r = wid * 32 + i * 8 + srow;
            GLDS16(B + (long long)(n0 + r) * ldb + k0 + scol, &Bs[wid * 32 + i * 8][0]);
        }
        __syncthreads();
        #pragma unroll
        for (int kk = 0; kk < 2; ++kk) {
            short8 af[4], bf[4];
            #pragma unroll
            for (int m = 0; m < 4; ++m)
                af[m] = *(const short8*)&As[wr * 64 + m * 16 + (lane & 15)][kk * 32 + (lane >> 4) * 8];
            #pragma unroll
            for (int n = 0; n < 4; ++n)
                bf[n] = *(const short8*)&Bs[wc * 64 + n * 16 + (lane & 15)][kk * 32 + (lane >> 4) * 8];
            #pragma unroll
            for (int m = 0; m < 4; ++m)
                #pragma unroll
                for (int n = 0; n < 4; ++n)
                    acc[m][n] = __builtin_amdgcn_mfma_f32_16x16x32_bf16(af[m], bf[n], acc[m][n], 0, 0, 0);
        }
        __syncthreads();
    }

    float sa = fmaxf(scal[ia] * (1.f / 127.f), 1e-8f);
    float sb = fmaxf(scal[ib] * (1.f / 127.f), 1e-8f);
    float ab = sa * sb;
    float so = (MODE == 2) ? fmaxf(scal[iout] * (1.f / 127.f), 1e-8f) : 1.f;
    float lmax = 0.f;
    #pragma unroll
    for (int m = 0; m < 4; ++m)
        #pragma unroll
        for (int n = 0; n < 4; ++n)
            #pragma unroll
            for (int r = 0; r < 4; ++r) {
                int row = m0 + wr * 64 + m * 16 + (lane >> 4) * 4 + r;
                int col = n0 + wc * 64 + n * 16 + (lane & 15);
                float y = ab * acc[m][n][r];
                if (bias) y += bias[col];
                if (MODE == 0)
                    ((float*)Cout)[coff + (long long)row * ldc + col] = y;
                if (MODE == 2) {
                    float qv = qclamp(rintf(y / so));
                    ((i8*)Cout)[coff + (long long)row * ldc + col] = (i8)(int)qv;
                }
                if (MODE <= 1) lmax = fmaxf(lmax, fabsf(y));
            }
    if (MODE <= 1) {
        #pragma unroll
        for (int off = 32; off; off >>= 1) lmax = fmaxf(lmax, __shfl_xor(lmax, off, 64));
        if (lane == 0) wred[wid] = lmax;
        __syncthreads();
        if (tid == 0) atomicMaxF(maxout, fmaxf(fmaxf(wred[0], wred[1]), fmaxf(wred[2], wred[3])));
    }
}

// ---------------- softmax stats: wave per row ----------------
__global__ __launch_bounds__(256) void softmax_stats(const i8* __restrict__ qS,
                                                     const float* __restrict__ scal,
                                                     float* __restrict__ rowM, float* __restrict__ rowZ,
                                                     float* __restrict__ pmax) {
    int lane = threadIdx.x & 63, wid = threadIdx.x >> 6;
    long long row = (long long)blockIdx.x * 4 + wid;
    const i8* p = qS + row * SEQ + lane * 16;
    float ss = fmaxf(scal[10] * (1.f / 127.f), 1e-8f);
    float c = ss * 0.125f;
    union { int4 q; i8 b[16]; } u;
    u.q = *(const int4*)p;
    float m = -1e30f;
    #pragma unroll
    for (int j = 0; j < 16; ++j) m = fmaxf(m, (float)u.b[j]);
    #pragma unroll
    for (int off = 32; off; off >>= 1) m = fmaxf(m, __shfl_xor(m, off, 64));
    float zz = 0.f;
    #pragma unroll
    for (int j = 0; j < 16; ++j) zz += expf(c * ((float)u.b[j] - m));
    #pragma unroll
    for (int off = 32; off; off >>= 1) zz += __shfl_xor(zz, off, 64);
    __shared__ float sm[4];
    if (lane == 0) { rowM[row] = m; rowZ[row] = zz; sm[wid] = 1.f / zz; }
    __syncthreads();
    if (threadIdx.x == 0) atomicMaxF(pmax, fmaxf(fmaxf(sm[0], sm[1]), fmaxf(sm[2], sm[3])));
}

// ---------------- PV GEMM with fused softmax+prob-quant on A-staging ----------------
// A = probs(qS rows) quantized on the fly; B = V codes (K x N, transposed into LDS).
// 256x64 tile, 4 waves stacked on M. Writes f32 attn to Y[b][token][h*64+d] + max.
__global__ __launch_bounds__(256) void gemm_pv(
    const i8* __restrict__ S, const u16* __restrict__ V, float* __restrict__ Y,
    const float* __restrict__ rowM, const float* __restrict__ rowZ,
    const float* __restrict__ scal, float* __restrict__ maxout)
{
    __shared__ u16 As[256][64];
    __shared__ u16 Bs[64][64];
    __shared__ float wred[4];

    int z = blockIdx.z, zb = z >> 4, zh = z & 15;
    const i8* Sz = S + (long long)z * SEQ * SEQ;
    const u16* Vz = V + (long long)zb * SEQ * KD + zh * HDIM;
    float* Yz = Y + (long long)zb * SEQ * KD + zh * HDIM;
    const float* rM = rowM + (long long)z * SEQ;
    const float* rZ = rowZ + (long long)z * SEQ;

    float ss = fmaxf(scal[10] * (1.f / 127.f), 1e-8f);
    float cc = ss * 0.125f;
    float sp = fmaxf(scal[11] * (1.f / 127.f), 1e-8f);
    float sv = fmaxf(scal[9]  * (1.f / 127.f), 1e-8f);

    int tid = threadIdx.x, lane = tid & 63, wid = tid >> 6;
    int m0 = blockIdx.y * 256;

    f32x4 acc[4][4];
    #pragma unroll
    for (int m = 0; m < 4; ++m)
        #pragma unroll
        for (int n = 0; n < 4; ++n) acc[m][n] = (f32x4)0.0f;

    for (int k0 = 0; k0 < SEQ; k0 += 64) {
        // A: 256x64 prob codes (exp + /Z + /sp quant, matching reference division order)
        #pragma unroll
        for (int i = 0; i < 4; ++i) {
            int lin = tid + i * 256;
            int r = lin >> 2, c = (lin & 3) * 16;
            int grow = m0 + r;
            union { int4 q; i8 b[16]; } u;
            u.q = *(const int4*)(Sz + (long long)grow * SEQ + k0 + c);
            float m = rM[grow], Z = rZ[grow];
            alignas(16) u16 o[16];
            #pragma unroll
            for (int j = 0; j < 16; ++j) {
                float pr = expf(cc * ((float)u.b[j] - m)) / Z;
                o[j] = f2c(qclamp(rintf(pr / sp)));
            }
            *(int4*)&As[r][c]     = ((int4*)o)[0];
            *(int4*)&As[r][c + 8] = ((int4*)o)[1];
        }
        // B: V[k0..+63][0..63] transposed into Bs[d][k]
        {
            int r = tid >> 2, c = (tid & 3) * 16;
            union { int4 q; u16 w[8]; } u0, u1;
            u0.q = *(const int4*)(Vz + (long long)(k0 + r) * KD + c);
            u1.q = *(const int4*)(Vz + (long long)(k0 + r) * KD + c + 8);
            #pragma unroll
            for (int j = 0; j < 8; ++j) Bs[c + j][r] = u0.w[j];
            #pragma unroll
            for (int j = 0; j < 8; ++j) Bs[c + 8 + j][r] = u1.w[j];
        }
        __syncthreads();
        #pragma unroll
        for (int kk = 0; kk < 2; ++kk) {
            short8 af[4], bf[4];
            #pragma unroll
            for (int m = 0; m < 4; ++m)
                af[m] = *(const short8*)&As[wid * 64 + m * 16 + (lane & 15)][kk * 32 + (lane >> 4) * 8];
            #pragma unroll
            for (int n = 0; n < 4; ++n)
                bf[n] = *(const short8*)&Bs[n * 16 + (lane & 15)][kk * 32 + (lane >> 4) * 8];
            #pragma unroll
            for (int m = 0; m < 4; ++m)
                #pragma unroll
                for (int n = 0; n < 4; ++n)
                    acc[m][n] = __builtin_amdgcn_mfma_f32_16x16x32_bf16(af[m], bf[n], acc[m][n], 0, 0, 0);
        }
        __syncthreads();
    }

    float ab = sp * sv;
    float lmax = 0.f;
    #pragma unroll
    for (int m = 0; m < 4; ++m)
        #pragma unroll
        for (int n = 0; n < 4; ++n)
            #pragma unroll
            for (int r = 0; r < 4; ++r) {
                int row = m0 + wid * 64 + m * 16 + (lane >> 4) * 4 + r;
                int col = n * 16 + (lane & 15);
                float y = ab * acc[m][n][r];
                Yz[(long long)row * KD + col] = y;
                lmax = fmaxf(lmax, fabsf(y));
            }
    #pragma unroll
    for (int off = 32; off; off >>= 1) lmax = fmaxf(lmax, __shfl_xor(lmax, off, 64));
    if (lane == 0) wred[wid] = lmax;
    __syncthreads();
    if (tid == 0) atomicMaxF(maxout, fmaxf(fmaxf(wred[0], wred[1]), fmaxf(wred[2], wred[3])));
}

// ---------------- residual + LayerNorm (one row per block, float4) ----------------
template<bool WMAX>
__global__ __launch_bounds__(256) void ln_res(const float* __restrict__ base, const u16* __restrict__ qadd,
                                              const float* __restrict__ scal, int isc,
                                              const float* __restrict__ g, const float* __restrict__ beta,
                                              float* __restrict__ out, float* __restrict__ xmax) {
    long long row = blockIdx.x;
    int tid = threadIdx.x, lane = tid & 63, wid = tid >> 6;
    float s = fmaxf(scal[isc] * (1.f / 127.f), 1e-8f);
    float4 v = ((const float4*)(base + row * KD))[tid];
    ushort4 qq = ((const ushort4*)(qadd + row * KD))[tid];
    v.x += c2f(qq.x) * s; v.y += c2f(qq.y) * s; v.z += c2f(qq.z) * s; v.w += c2f(qq.w) * s;
    float sum = v.x + v.y + v.z + v.w;
    float sq  = v.x * v.x + v.y * v.y + v.z * v.z + v.w * v.w;
    #pragma unroll
    for (int off = 32; off; off >>= 1) { sum += __shfl_xor(sum, off, 64); sq += __shfl_xor(sq, off, 64); }
    __shared__ float s1[4], s2[4];
    if (lane == 0) { s1[wid] = sum; s2[wid] = sq; }
    __syncthreads();
    sum = s1[0] + s1[1] + s1[2] + s1[3];
    sq  = s2[0] + s2[1] + s2[2] + s2[3];
    float mu  = sum * (1.f / 1024.f);
    float var = sq * (1.f / 1024.f) - mu * mu;
    float inv = 1.f / sqrtf(var + 1e-5f);
    float4 gv = ((const float4*)g)[tid];
    float4 bv = ((const float4*)beta)[tid];
    float4 o;
    o.x = (v.x - mu) * inv * gv.x + bv.x;
    o.y = (v.y - mu) * inv * gv.y + bv.y;
    o.z = (v.z - mu) * inv * gv.z + bv.z;
    o.w = (v.w - mu) * inv * gv.w + bv.w;
    ((float4*)(out + row * KD))[tid] = o;
    if (WMAX) {
        float lm = fmaxf(fmaxf(fabsf(o.x), fabsf(o.y)), fmaxf(fabsf(o.z), fabsf(o.w)));
        #pragma unroll
        for (int off = 32; off; off >>= 1) lm = fmaxf(lm, __shfl_xor(lm, off, 64));
        __syncthreads();
        if (lane == 0) s1[wid] = lm;
        __syncthreads();
        if (tid == 0) atomicMaxF(xmax, fmaxf(fmaxf(s1[0], s1[1]), fmaxf(s1[2], s1[3])));
    }
}

// ---------------- FFN mid: quantize y -> codes, track max of relu(fq(y)) ----------------
__global__ __launch_bounds__(256) void relu_quant_a(const float4* __restrict__ y,
                                                    const float* __restrict__ scal,
                                                    ushort4* __restrict__ qh, float* __restrict__ rmax) {
    long long i = (long long)blockIdx.x * 256 + threadIdx.x;
    float s = fmaxf(scal[15] * (1.f / 127.f), 1e-8f);
    float4 v = y[i];
    float q0 = qclamp(rintf(v.x / s)), q1 = qclamp(rintf(v.y / s));
    float q2 = qclamp(rintf(v.z / s)), q3 = qclamp(rintf(v.w / s));
    ushort4 o; o.x = f2c(q0); o.y = f2c(q1); o.z = f2c(q2); o.w = f2c(q3);
    qh[i] = o;
    float lm = fmaxf(fmaxf(q0, q1), fmaxf(q2, q3));
    lm = fmaxf(lm, 0.f) * s;
    #pragma unroll
    for (int off = 32; off; off >>= 1) lm = fmaxf(lm, __shfl_xor(lm, off, 64));
    __shared__ float sm[4];
    int lane = threadIdx.x & 63, wid = threadIdx.x >> 6;
    if (lane == 0) sm[wid] = lm;
    __syncthreads();
    if (threadIdx.x == 0) atomicMaxF(rmax, fmaxf(fmaxf(sm[0], sm[1]), fmaxf(sm[2], sm[3])));
}

__global__ __launch_bounds__(256) void relu_quant_b(ushort4* __restrict__ qh,
                                                    const float* __restrict__ scal) {
    long long i = (long long)blockIdx.x * 256 + threadIdx.x;
    float s  = fmaxf(scal[15] * (1.f / 127.f), 1e-8f);
    float sr = fmaxf(scal[16] * (1.f / 127.f), 1e-8f);
    ushort4 q = qh[i];
    ushort4 o;
    o.x = f2c(qclamp(rintf(fmaxf(c2f(q.x), 0.f) * s / sr)));
    o.y = f2c(qclamp(rintf(fmaxf(c2f(q.y), 0.f) * s / sr)));
    o.z = f2c(qclamp(rintf(fmaxf(c2f(q.z), 0.f) * s / sr)));
    o.w = f2c(qclamp(rintf(fmaxf(c2f(q.w), 0.f) * s / sr)));
    qh[i] = o;
}

// ---------------- launch ----------------
extern "C" void kernel_launch(void* const* d_in, const int* in_sizes, int n_in,
                              void* d_out, int out_size, void* d_ws, size_t ws_size,
                              hipStream_t stream) {
    const float* src = (const float*)d_in[0];
    const float* wq  = (const float*)d_in[1];
    const float* wk  = (const float*)d_in[2];
    const float* wv_ = (const float*)d_in[3];
    const float* wo  = (const float*)d_in[4];
    const float* w1  = (const float*)d_in[5];
    const float* b1  = (const float*)d_in[6];
    const float* w2  = (const float*)d_in[7];
    const float* b2  = (const float*)d_in[8];
    const float* g1  = (const float*)d_in[9];
    const float* bb1 = (const float*)d_in[10];
    const float* g2  = (const float*)d_in[11];
    const float* bb2 = (const float*)d_in[12];
    float* out = (float*)d_out;
    (void)in_sizes; (void)n_in; (void)out_size; (void)ws_size;

    char* ws = (char*)d_ws;
    size_t off = 0;
    auto alloc = [&](size_t bytes) -> char* {
        char* p = ws + off;
        off = (off + bytes + 255) & ~(size_t)255;
        return p;
    };
    float* scal = (float*)alloc(256);
    float* rowM = (float*)alloc(AROWS * 4);
    float* rowZ = (float*)alloc(AROWS * 4);
    u16* qsrc = (u16*)alloc((size_t)ROWS * KD * 2);   // later reused as qX
    u16* qwq  = (u16*)alloc((size_t)KD * KD * 2);
    u16* qwk  = (u16*)alloc((size_t)KD * KD * 2);
    u16* qwv  = (u16*)alloc((size_t)KD * KD * 2);
    u16* qwo  = (u16*)alloc((size_t)KD * KD * 2);
    u16* qw1  = (u16*)alloc((size_t)DFF * KD * 2);
    u16* qw2  = (u16*)alloc((size_t)KD * DFF * 2);
    u16* qQ   = (u16*)alloc((size_t)ROWS * KD * 2);   // later reused as qA
    u16* qK   = (u16*)alloc((size_t)ROWS * KD * 2);   // later reused as qAo
    u16* qV   = (u16*)alloc((size_t)ROWS * KD * 2);   // later reused as qFF
    u16* qH   = (u16*)alloc((size_t)ROWS * DFF * 2);
    i8*  qS   = (i8*)alloc((size_t)NBATCH * NH * SEQ * SEQ);
    float* xbuf = (float*)alloc((size_t)ROWS * KD * 4);
    float* ybuf = (float*)alloc((size_t)ROWS * DFF * 4);
    u16* qX  = qsrc;
    u16* qA  = qQ;
    u16* qAo = qK;
    u16* qFF = qV;

    hipMemsetAsync(scal, 0, 256, stream);

    // 1. absmax of f32 inputs
    absmax_f32<<<1024, 256, 0, stream>>>((const float4*)src, (long long)ROWS * KD / 4, &scal[0]);
    absmax_f32<<<512, 256, 0, stream>>>((const float4*)wq,  (long long)KD * KD / 4, &scal[1]);
    absmax_f32<<<512, 256, 0, stream>>>((const float4*)wk,  (long long)KD * KD / 4, &scal[2]);
    absmax_f32<<<512, 256, 0, stream>>>((const float4*)wv_, (long long)KD * KD / 4, &scal[3]);
    absmax_f32<<<512, 256, 0, stream>>>((const float4*)wo,  (long long)KD * KD / 4, &scal[4]);
    absmax_f32<<<1024, 256, 0, stream>>>((const float4*)w1, (long long)DFF * KD / 4, &scal[5]);
    absmax_f32<<<1024, 256, 0, stream>>>((const float4*)w2, (long long)KD * DFF / 4, &scal[6]);

    // 2. quantize to bf16 codes
    quant_to_bf16<<<4096, 256, 0, stream>>>((const float4*)src, &scal[0], (ushort4*)qsrc);
    quant_to_bf16<<<1024, 256, 0, stream>>>((const float4*)wq,  &scal[1], (ushort4*)qwq);
    quant_to_bf16<<<1024, 256, 0, stream>>>((const float4*)wk,  &scal[2], (ushort4*)qwk);
    quant_to_bf16<<<1024, 256, 0, stream>>>((const float4*)wv_, &scal[3], (ushort4*)qwv);
    quant_to_bf16<<<1024, 256, 0, stream>>>((const float4*)wo,  &scal[4], (ushort4*)qwo);
    quant_to_bf16<<<4096, 256, 0, stream>>>((const float4*)w1,  &scal[5], (ushort4*)qw1);
    quant_to_bf16<<<4096, 256, 0, stream>>>((const float4*)w2,  &scal[6], (ushort4*)qw2);

    // 3. Q/K/V projections
    dim3 gP(KD / 128, ROWS / 128, 1);
    gemm_mfma<0><<<gP, 256, 0, stream>>>(qsrc, KD, 0, 0, qwq, KD, 0, 0, ybuf, KD, 0, 0,
                                         KD, 1, scal, 0, 1, -1, nullptr, &scal[7]);
    quant_to_bf16<<<4096, 256, 0, stream>>>((const float4*)ybuf, &scal[7], (ushort4*)qQ);
    gemm_mfma<0><<<gP, 256, 0, stream>>>(qsrc, KD, 0, 0, qwk, KD, 0, 0, ybuf, KD, 0, 0,
                                         KD, 1, scal, 0, 2, -1, nullptr, &scal[8]);
    quant_to_bf16<<<4096, 256, 0, stream>>>((const float4*)ybuf, &scal[8], (ushort4*)qK);
    gemm_mfma<0><<<gP, 256, 0, stream>>>(qsrc, KD, 0, 0, qwv, KD, 0, 0, ybuf, KD, 0, 0,
                                         KD, 1, scal, 0, 3, -1, nullptr, &scal[9]);
    quant_to_bf16<<<4096, 256, 0, stream>>>((const float4*)ybuf, &scal[9], (ushort4*)qV);

    // 4. scores: pass1 max only, pass2 quantize to int8
    dim3 gS(SEQ / 128, SEQ / 128, NBATCH * NH);
    const long long sQb = (long long)SEQ * KD;
    const long long sSb = (long long)NH * SEQ * SEQ;
    const long long sSh = (long long)SEQ * SEQ;
    gemm_mfma<1><<<gS, 256, 0, stream>>>(qQ, KD, sQb, HDIM, qK, KD, sQb, HDIM,
                                         nullptr, SEQ, sSb, sSh,
                                         HDIM, NH, scal, 7, 8, -1, nullptr, &scal[10]);
    gemm_mfma<2><<<gS, 256, 0, stream>>>(qQ, KD, sQb, HDIM, qK, KD, sQb, HDIM,
                                         qS, SEQ, sSb, sSh,
                                         HDIM, NH, scal, 7, 8, 10, nullptr, nullptr);

    // 5. softmax stats (rowM, rowZ, pmax)
    softmax_stats<<<(unsigned)(AROWS / 4), 256, 0, stream>>>(qS, scal, rowM, rowZ, &scal[11]);

    // 6. attn = fq(probs) @ fq(v)  (softmax+quant fused into A staging)
    dim3 gV(1, SEQ / 256, NBATCH * NH);
    gemm_pv<<<gV, 256, 0, stream>>>(qS, qV, ybuf, rowM, rowZ, scal, &scal[12]);
    quant_to_bf16<<<4096, 256, 0, stream>>>((const float4*)ybuf, &scal[12], (ushort4*)qA);

    // 7. output projection
    gemm_mfma<0><<<gP, 256, 0, stream>>>(qA, KD, 0, 0, qwo, KD, 0, 0, ybuf, KD, 0, 0,
                                         KD, 1, scal, 12, 4, -1, nullptr, &scal[13]);
    quant_to_bf16<<<4096, 256, 0, stream>>>((const float4*)ybuf, &scal[13], (ushort4*)qAo);

    // 8. residual + LN1
    ln_res<true><<<ROWS, 256, 0, stream>>>(src, qAo, scal, 13, g1, bb1, xbuf, &scal[14]);
    quant_to_bf16<<<4096, 256, 0, stream>>>((const float4*)xbuf, &scal[14], (ushort4*)qX);

    // 9. FFN1 + quant + relu + requant
    dim3 gF1(DFF / 128, ROWS / 128, 1);
    gemm_mfma<0><<<gF1, 256, 0, stream>>>(qX, KD, 0, 0, qw1, KD, 0, 0, ybuf, DFF, 0, 0,
                                          KD, 1, scal, 14, 5, -1, b1, &scal[15]);
    relu_quant_a<<<16384, 256, 0, stream>>>((const float4*)ybuf, scal, (ushort4*)qH, &scal[16]);
    relu_quant_b<<<16384, 256, 0, stream>>>((ushort4*)qH, scal);

    // 10. FFN2
    dim3 gF2(KD / 128, ROWS / 128, 1);
    gemm_mfma<0><<<gF2, 256, 0, stream>>>(qH, DFF, 0, 0, qw2, DFF, 0, 0, ybuf, KD, 0, 0,
                                          DFF, 1, scal, 16, 6, -1, b2, &scal[17]);
    quant_to_bf16<<<4096, 256, 0, stream>>>((const float4*)ybuf, &scal[17], (ushort4*)qFF);

    // 11. residual + LN2 -> out
    ln_res<false><<<ROWS, 256, 0, stream>>>(xbuf, qFF, scal, 17, g2, bb2, out, nullptr);
}

// Round 6
// 852.807 us; speedup vs baseline: 4.4574x; 1.4720x over previous
//
#include <hip/hip_runtime.h>
#include <cstdint>

// Problem constants
constexpr int KD   = 1024;
constexpr int NH   = 16;
constexpr int HDIM = 64;
constexpr int DFF  = 4096;
constexpr int NBATCH = 4;
constexpr int SEQ  = 1024;
constexpr int ROWS = NBATCH * SEQ;                       // 4096
constexpr long long AROWS = (long long)NBATCH * NH * SEQ; // 65536

typedef signed char i8;
typedef unsigned short u16;
typedef __attribute__((ext_vector_type(8))) short short8;
typedef __attribute__((ext_vector_type(4))) float f32x4;

__device__ __forceinline__ void atomicMaxF(float* a, float v) {
    atomicMax((unsigned int*)a, __float_as_uint(v));   // valid: values >= 0, buffer zeroed
}
// int8 code values are exact in bf16: low 16 bits of their f32 pattern are zero.
__device__ __forceinline__ float c2f(u16 u) { return __uint_as_float(((unsigned)u) << 16); }
__device__ __forceinline__ u16   f2c(float f) { return (u16)(__float_as_uint(f) >> 16); }
__device__ __forceinline__ float qclamp(float x) { return fminf(fmaxf(x, -128.f), 127.f); }

#define GLDS16(gp, lp) __builtin_amdgcn_global_load_lds( \
    (const __attribute__((address_space(1))) void*)(gp), \
    (__attribute__((address_space(3))) void*)(lp), 16, 0, 0)

// ---------------- batched absmax + quant for the 7 f32 inputs ----------------
struct Batch7 {
    const float4* x[7];
    ushort4*      q[7];
    long long     n4[7];
};

__global__ __launch_bounds__(256) void absmax_multi(Batch7 b7, float* __restrict__ scal) {
    int t = blockIdx.y;
    const float4* __restrict__ x = b7.x[t];
    long long n4 = b7.n4[t];
    float m = 0.f;
    for (long long i = (long long)blockIdx.x * 256 + threadIdx.x; i < n4;
         i += (long long)gridDim.x * 256) {
        float4 v = x[i];
        m = fmaxf(m, fmaxf(fmaxf(fabsf(v.x), fabsf(v.y)), fmaxf(fabsf(v.z), fabsf(v.w))));
    }
    #pragma unroll
    for (int off = 32; off; off >>= 1) m = fmaxf(m, __shfl_xor(m, off, 64));
    __shared__ float sm[4];
    int lane = threadIdx.x & 63, wid = threadIdx.x >> 6;
    if (lane == 0) sm[wid] = m;
    __syncthreads();
    if (threadIdx.x == 0) atomicMaxF(&scal[t], fmaxf(fmaxf(sm[0], sm[1]), fmaxf(sm[2], sm[3])));
}

__global__ __launch_bounds__(256) void quant_multi(Batch7 b7, const float* __restrict__ scal) {
    int t = blockIdx.y;
    const float4* __restrict__ x = b7.x[t];
    ushort4* __restrict__ q = b7.q[t];
    long long n4 = b7.n4[t];
    float s = fmaxf(scal[t] * (1.f / 127.f), 1e-8f);
    for (long long i = (long long)blockIdx.x * 256 + threadIdx.x; i < n4;
         i += (long long)gridDim.x * 256) {
        float4 v = x[i];
        ushort4 o;
        o.x = f2c(qclamp(rintf(v.x / s)));
        o.y = f2c(qclamp(rintf(v.y / s)));
        o.z = f2c(qclamp(rintf(v.z / s)));
        o.w = f2c(qclamp(rintf(v.w / s)));
        q[i] = o;
    }
}

// ---------------- quantize f32 -> bf16 code bits (exact grid: n/1024 blocks) ----------------
__global__ __launch_bounds__(256) void quant_to_bf16(const float4* __restrict__ x,
                                                     const float* __restrict__ mp,
                                                     ushort4* __restrict__ q) {
    long long i = (long long)blockIdx.x * 256 + threadIdx.x;
    float s = fmaxf(mp[0] * (1.f / 127.f), 1e-8f);
    float4 v = x[i];
    ushort4 o;
    o.x = f2c(qclamp(rintf(v.x / s)));
    o.y = f2c(qclamp(rintf(v.y / s)));
    o.z = f2c(qclamp(rintf(v.z / s)));
    o.w = f2c(qclamp(rintf(v.w / s)));
    q[i] = o;
}

// ---------------- fused quant + transpose of V:  VT[b*16+h][d][k] = codes(V[b][k][h*64+d]) ----
__global__ __launch_bounds__(256) void quant_v_t(const float* __restrict__ y,
                                                 const float* __restrict__ mp,
                                                 u16* __restrict__ VT) {
    __shared__ u16 t[64][66];                      // +2 pad: col-read stride 33 banks == 1 mod 32
    float s = fmaxf(mp[0] * (1.f / 127.f), 1e-8f);
    int kt = blockIdx.x, h = blockIdx.y, b = blockIdx.z;
    int tid = threadIdx.x;
    int r = tid >> 2, c0 = (tid & 3) * 16;
    const float* base = y + ((long long)(b * SEQ + kt * 64 + r)) * KD + h * 64 + c0;
    #pragma unroll
    for (int v4 = 0; v4 < 4; ++v4) {
        float4 v = ((const float4*)base)[v4];
        t[r][c0 + v4 * 4 + 0] = f2c(qclamp(rintf(v.x / s)));
        t[r][c0 + v4 * 4 + 1] = f2c(qclamp(rintf(v.y / s)));
        t[r][c0 + v4 * 4 + 2] = f2c(qclamp(rintf(v.z / s)));
        t[r][c0 + v4 * 4 + 3] = f2c(qclamp(rintf(v.w / s)));
    }
    __syncthreads();
    int rr = tid >> 2, cc = (tid & 3) * 16;        // rr = d, cc = k offset
    alignas(16) u16 o[16];
    #pragma unroll
    for (int j = 0; j < 16; ++j) o[j] = t[cc + j][rr];
    u16* ob = VT + ((long long)(b * NH + h) * HDIM + rr) * SEQ + kt * 64 + cc;
    ((int4*)ob)[0] = ((int4*)o)[0];
    ((int4*)ob)[1] = ((int4*)o)[1];
}

// ---------------- MFMA GEMM on bf16 codes: C = sa*sb*(A @ B^T) (+bias) ----------------
// 128x128 tile, BK=64, 4 waves (2x2 of 64x64), global_load_lds staging (m97 structure).
// MODE 0: write f32 + track max; 1: max only; 2: write int8 quantized by scal[iout].
template<int MODE>
__global__ __launch_bounds__(256) void gemm_mfma(
    const u16* __restrict__ A, int lda, long long sAb, long long sAh,
    const u16* __restrict__ B, int ldb, long long sBb, long long sBh,
    void* __restrict__ Cout, int ldc, long long sCb, long long sCh,
    int Kg, int Hdiv,
    const float* __restrict__ scal, int ia, int ib, int iout,
    const float* __restrict__ bias, float* __restrict__ maxout)
{
    __shared__ u16 As[128][64];
    __shared__ u16 Bs[128][64];
    __shared__ float wred[4];

    int z = blockIdx.z, zb = z / Hdiv, zh = z % Hdiv;
    A += (long long)zb * sAb + (long long)zh * sAh;
    B += (long long)zb * sBb + (long long)zh * sBh;
    long long coff = (long long)zb * sCb + (long long)zh * sCh;

    int tid = threadIdx.x, lane = tid & 63, wid = tid >> 6;
    int wr = wid >> 1, wc = wid & 1;
    int m0 = blockIdx.y * 128, n0 = blockIdx.x * 128;

    f32x4 acc[4][4];
    #pragma unroll
    for (int m = 0; m < 4; ++m)
        #pragma unroll
        for (int n = 0; n < 4; ++n) acc[m][n] = (f32x4)0.0f;

    int srow = lane >> 3;            // 0..7 row within 8-row slab
    int scol = (lane & 7) * 8;       // bf16 element col (16B chunk)

    for (int k0 = 0; k0 < Kg; k0 += 64) {
        #pragma unroll
        for (int i = 0; i < 4; ++i) {
            int r = wid * 32 + i * 8 + srow;
            GLDS16(A + (long long)(m0 + r) * lda + k0 + scol, &As[wid * 32 + i * 8][0]);
        }
        #pragma unroll
        for (int i = 0; i < 4; ++i) {
            int r = wid * 32 + i * 8 + srow;
            GLDS16(B + (long long)(n0 + r) * ldb + k0 + scol, &Bs[wid * 32 + i * 8][0]);
        }
        __syncthreads();
        #pragma unroll
        for (int kk = 0; kk < 2; ++kk) {
            short8 af[4], bf[4];
            #pragma unroll
            for (int m = 0; m < 4; ++m)
                af[m] = *(const short8*)&As[wr * 64 + m * 16 + (lane & 15)][kk * 32 + (lane >> 4) * 8];
            #pragma unroll
            for (int n = 0; n < 4; ++n)
                bf[n] = *(const short8*)&Bs[wc * 64 + n * 16 + (lane & 15)][kk * 32 + (lane >> 4) * 8];
            #pragma unroll
            for (int m = 0; m < 4; ++m)
                #pragma unroll
                for (int n = 0; n < 4; ++n)
                    acc[m][n] = __builtin_amdgcn_mfma_f32_16x16x32_bf16(af[m], bf[n], acc[m][n], 0, 0, 0);
        }
        __syncthreads();
    }

    float sa = fmaxf(scal[ia] * (1.f / 127.f), 1e-8f);
    float sb = fmaxf(scal[ib] * (1.f / 127.f), 1e-8f);
    float ab = sa * sb;
    float so = (MODE == 2) ? fmaxf(scal[iout] * (1.f / 127.f), 1e-8f) : 1.f;
    float lmax = 0.f;
    #pragma unroll
    for (int m = 0; m < 4; ++m)
        #pragma unroll
        for (int n = 0; n < 4; ++n)
            #pragma unroll
            for (int r = 0; r < 4; ++r) {
                int row = m0 + wr * 64 + m * 16 + (lane >> 4) * 4 + r;
                int col = n0 + wc * 64 + n * 16 + (lane & 15);
                float y = ab * acc[m][n][r];
                if (bias) y += bias[col];
                if (MODE == 0)
                    ((float*)Cout)[coff + (long long)row * ldc + col] = y;
                if (MODE == 2) {
                    float qv = qclamp(rintf(y / so));
                    ((i8*)Cout)[coff + (long long)row * ldc + col] = (i8)(int)qv;
                }
                if (MODE <= 1) lmax = fmaxf(lmax, fabsf(y));
            }
    if (MODE <= 1) {
        #pragma unroll
        for (int off = 32; off; off >>= 1) lmax = fmaxf(lmax, __shfl_xor(lmax, off, 64));
        if (lane == 0) wred[wid] = lmax;
        __syncthreads();
        if (tid == 0) atomicMaxF(maxout, fmaxf(fmaxf(wred[0], wred[1]), fmaxf(wred[2], wred[3])));
    }
}

// ---------------- softmax stats: wave per row, grid-stride 16 rows/wave, exact expf ----------
__global__ __launch_bounds__(256) void softmax_stats(const i8* __restrict__ qS,
                                                     const float* __restrict__ scal,
                                                     float* __restrict__ rowM, float* __restrict__ rowZ,
                                                     float* __restrict__ pmax) {
    int lane = threadIdx.x & 63, wid = threadIdx.x >> 6;
    int gw = blockIdx.x * 4 + wid;                   // 4096 waves total
    float ss = fmaxf(scal[10] * (1.f / 127.f), 1e-8f);
    float c = ss * 0.125f;
    float lpm = 0.f;
    for (long long row = gw; row < AROWS; row += 4096) {
        union { int4 q; i8 b[16]; } u;
        u.q = *(const int4*)(qS + row * SEQ + lane * 16);
        float m = -1e30f;
        #pragma unroll
        for (int j = 0; j < 16; ++j) m = fmaxf(m, (float)u.b[j]);
        #pragma unroll
        for (int off = 32; off; off >>= 1) m = fmaxf(m, __shfl_xor(m, off, 64));
        float zz = 0.f;
        #pragma unroll
        for (int j = 0; j < 16; ++j) zz += expf(c * ((float)u.b[j] - m));
        #pragma unroll
        for (int off = 32; off; off >>= 1) zz += __shfl_xor(zz, off, 64);
        if (lane == 0) { rowM[row] = m; rowZ[row] = zz; lpm = fmaxf(lpm, 1.f / zz); }
    }
    #pragma unroll
    for (int off = 32; off; off >>= 1) lpm = fmaxf(lpm, __shfl_xor(lpm, off, 64));
    __shared__ float sm[4];
    if (lane == 0) sm[wid] = lpm;
    __syncthreads();
    if (threadIdx.x == 0) atomicMaxF(pmax, fmaxf(fmaxf(sm[0], sm[1]), fmaxf(sm[2], sm[3])));
}

// ---------------- PV GEMM: A = fq(softmax(qS)) computed in staging, B = VT (global_load_lds) ---
// 128-row tile x 64 cols (full head), K-step 64, 4 waves each 32 rows.
// Math identical to passing R2: pr = expf(c*(s-m))/Z ; code = rintf(pr/sp).
__global__ __launch_bounds__(256) void gemm_pv(
    const i8* __restrict__ S, const u16* __restrict__ VT, float* __restrict__ Y,
    const float* __restrict__ rowM, const float* __restrict__ rowZ,
    const float* __restrict__ scal, float* __restrict__ maxout)
{
    __shared__ u16 As[128][64];
    __shared__ u16 Bs[64][64];
    __shared__ float wred[4];

    int z = blockIdx.z, zb = z >> 4, zh = z & 15;
    const i8* Sz = S + (long long)z * SEQ * SEQ;
    const u16* VTz = VT + (long long)z * HDIM * SEQ;
    float* Yz = Y + (long long)zb * SEQ * KD + zh * HDIM;
    const float* rM = rowM + (long long)z * SEQ;
    const float* rZ = rowZ + (long long)z * SEQ;

    float ss = fmaxf(scal[10] * (1.f / 127.f), 1e-8f);
    float cc = ss * 0.125f;
    float sp = fmaxf(scal[11] * (1.f / 127.f), 1e-8f);
    float sv = fmaxf(scal[9]  * (1.f / 127.f), 1e-8f);

    int tid = threadIdx.x, lane = tid & 63, wid = tid >> 6;
    int m0 = blockIdx.y * 128;

    // each thread owns one A row (two threads per row: col halves 0/32)
    int arow = tid >> 1;
    int acol = (tid & 1) * 32;
    int grow = m0 + arow;
    float mrow = rM[grow];        // per-head stats (head-offset bug fixed)
    float Zrow = rZ[grow];

    f32x4 acc[2][4];
    #pragma unroll
    for (int m = 0; m < 2; ++m)
        #pragma unroll
        for (int n = 0; n < 4; ++n) acc[m][n] = (f32x4)0.0f;

    int srow = lane >> 3, scol = (lane & 7) * 8;

    for (int k0 = 0; k0 < SEQ; k0 += 64) {
        // B: 64x64 VT rows via global_load_lds (2 slabs of 8 rows per wave)
        #pragma unroll
        for (int i = 0; i < 2; ++i) {
            int r = wid * 16 + i * 8;
            GLDS16(VTz + (long long)(r + srow) * SEQ + k0 + scol, &Bs[r][0]);
        }
        // A: compute 32 prob codes for this thread's row-half (exact R2 math)
        {
            union { int4 q; i8 b[16]; } u0, u1;
            const i8* sp_ = Sz + (long long)grow * SEQ + k0 + acol;
            u0.q = ((const int4*)sp_)[0];
            u1.q = ((const int4*)sp_)[1];
            alignas(16) u16 o[32];
            #pragma unroll
            for (int j = 0; j < 16; ++j) {
                float pr = expf(cc * ((float)u0.b[j] - mrow)) / Zrow;
                o[j] = f2c(qclamp(rintf(pr / sp)));
            }
            #pragma unroll
            for (int j = 0; j < 16; ++j) {
                float pr = expf(cc * ((float)u1.b[j] - mrow)) / Zrow;
                o[16 + j] = f2c(qclamp(rintf(pr / sp)));
            }
            #pragma unroll
            for (int j = 0; j < 4; ++j)
                ((int4*)&As[arow][acol])[j] = ((int4*)o)[j];
        }
        __syncthreads();
        #pragma unroll
        for (int kk = 0; kk < 2; ++kk) {
            short8 af[2], bf[4];
            #pragma unroll
            for (int m = 0; m < 2; ++m)
                af[m] = *(const short8*)&As[wid * 32 + m * 16 + (lane & 15)][kk * 32 + (lane >> 4) * 8];
            #pragma unroll
            for (int n = 0; n < 4; ++n)
                bf[n] = *(const short8*)&Bs[n * 16 + (lane & 15)][kk * 32 + (lane >> 4) * 8];
            #pragma unroll
            for (int m = 0; m < 2; ++m)
                #pragma unroll
                for (int n = 0; n < 4; ++n)
                    acc[m][n] = __builtin_amdgcn_mfma_f32_16x16x32_bf16(af[m], bf[n], acc[m][n], 0, 0, 0);
        }
        __syncthreads();
    }

    float ab = sp * sv;
    float lmax = 0.f;
    #pragma unroll
    for (int m = 0; m < 2; ++m)
        #pragma unroll
        for (int n = 0; n < 4; ++n)
            #pragma unroll
            for (int r = 0; r < 4; ++r) {
                int row = m0 + wid * 32 + m * 16 + (lane >> 4) * 4 + r;
                int col = n * 16 + (lane & 15);
                float y = ab * acc[m][n][r];
                Yz[(long long)row * KD + col] = y;
                lmax = fmaxf(lmax, fabsf(y));
            }
    #pragma unroll
    for (int off = 32; off; off >>= 1) lmax = fmaxf(lmax, __shfl_xor(lmax, off, 64));
    if (lane == 0) wred[wid] = lmax;
    __syncthreads();
    if (tid == 0) atomicMaxF(maxout, fmaxf(fmaxf(wred[0], wred[1]), fmaxf(wred[2], wred[3])));
}

// ---------------- residual + LayerNorm (one row per block, float4) ----------------
template<bool WMAX>
__global__ __launch_bounds__(256) void ln_res(const float* __restrict__ base, const u16* __restrict__ qadd,
                                              const float* __restrict__ scal, int isc,
                                              const float* __restrict__ g, const float* __restrict__ beta,
                                              float* __restrict__ out, float* __restrict__ xmax) {
    long long row = blockIdx.x;
    int tid = threadIdx.x, lane = tid & 63, wid = tid >> 6;
    float s = fmaxf(scal[isc] * (1.f / 127.f), 1e-8f);
    float4 v = ((const float4*)(base + row * KD))[tid];
    ushort4 qq = ((const ushort4*)(qadd + row * KD))[tid];
    v.x += c2f(qq.x) * s; v.y += c2f(qq.y) * s; v.z += c2f(qq.z) * s; v.w += c2f(qq.w) * s;
    float sum = v.x + v.y + v.z + v.w;
    float sq  = v.x * v.x + v.y * v.y + v.z * v.z + v.w * v.w;
    #pragma unroll
    for (int off = 32; off; off >>= 1) { sum += __shfl_xor(sum, off, 64); sq += __shfl_xor(sq, off, 64); }
    __shared__ float s1[4], s2[4];
    if (lane == 0) { s1[wid] = sum; s2[wid] = sq; }
    __syncthreads();
    sum = s1[0] + s1[1] + s1[2] + s1[3];
    sq  = s2[0] + s2[1] + s2[2] + s2[3];
    float mu  = sum * (1.f / 1024.f);
    float var = sq * (1.f / 1024.f) - mu * mu;
    float inv = 1.f / sqrtf(var + 1e-5f);
    float4 gv = ((const float4*)g)[tid];
    float4 bv = ((const float4*)beta)[tid];
    float4 o;
    o.x = (v.x - mu) * inv * gv.x + bv.x;
    o.y = (v.y - mu) * inv * gv.y + bv.y;
    o.z = (v.z - mu) * inv * gv.z + bv.z;
    o.w = (v.w - mu) * inv * gv.w + bv.w;
    ((float4*)(out + row * KD))[tid] = o;
    if (WMAX) {
        float lm = fmaxf(fmaxf(fabsf(o.x), fabsf(o.y)), fmaxf(fabsf(o.z), fabsf(o.w)));
        #pragma unroll
        for (int off = 32; off; off >>= 1) lm = fmaxf(lm, __shfl_xor(lm, off, 64));
        __syncthreads();
        if (lane == 0) s1[wid] = lm;
        __syncthreads();
        if (tid == 0) atomicMaxF(xmax, fmaxf(fmaxf(s1[0], s1[1]), fmaxf(s1[2], s1[3])));
    }
}

// ---------------- FFN mid: quantize y -> codes, track max of relu(fq(y)) ----------------
__global__ __launch_bounds__(256) void relu_quant_a(const float4* __restrict__ y,
                                                    const float* __restrict__ scal,
                                                    ushort4* __restrict__ qh, float* __restrict__ rmax) {
    constexpr long long N4 = (long long)ROWS * DFF / 4;
    float s = fmaxf(scal[15] * (1.f / 127.f), 1e-8f);
    float lm = 0.f;
    for (long long i = (long long)blockIdx.x * 256 + threadIdx.x; i < N4;
         i += (long long)gridDim.x * 256) {
        float4 v = y[i];
        float q0 = qclamp(rintf(v.x / s)), q1 = qclamp(rintf(v.y / s));
        float q2 = qclamp(rintf(v.z / s)), q3 = qclamp(rintf(v.w / s));
        ushort4 o; o.x = f2c(q0); o.y = f2c(q1); o.z = f2c(q2); o.w = f2c(q3);
        qh[i] = o;
        lm = fmaxf(lm, fmaxf(fmaxf(q0, q1), fmaxf(q2, q3)));
    }
    lm = fmaxf(lm, 0.f) * s;
    #pragma unroll
    for (int off = 32; off; off >>= 1) lm = fmaxf(lm, __shfl_xor(lm, off, 64));
    __shared__ float sm[4];
    int lane = threadIdx.x & 63, wid = threadIdx.x >> 6;
    if (lane == 0) sm[wid] = lm;
    __syncthreads();
    if (threadIdx.x == 0) atomicMaxF(rmax, fmaxf(fmaxf(sm[0], sm[1]), fmaxf(sm[2], sm[3])));
}

__global__ __launch_bounds__(256) void relu_quant_b(ushort4* __restrict__ qh,
                                                    const float* __restrict__ scal) {
    constexpr long long N4 = (long long)ROWS * DFF / 4;
    float s  = fmaxf(scal[15] * (1.f / 127.f), 1e-8f);
    float sr = fmaxf(scal[16] * (1.f / 127.f), 1e-8f);
    for (long long i = (long long)blockIdx.x * 256 + threadIdx.x; i < N4;
         i += (long long)gridDim.x * 256) {
        ushort4 q = qh[i];
        ushort4 o;
        o.x = f2c(qclamp(rintf(fmaxf(c2f(q.x), 0.f) * s / sr)));
        o.y = f2c(qclamp(rintf(fmaxf(c2f(q.y), 0.f) * s / sr)));
        o.z = f2c(qclamp(rintf(fmaxf(c2f(q.z), 0.f) * s / sr)));
        o.w = f2c(qclamp(rintf(fmaxf(c2f(q.w), 0.f) * s / sr)));
        qh[i] = o;
    }
}

// ---------------- launch ----------------
extern "C" void kernel_launch(void* const* d_in, const int* in_sizes, int n_in,
                              void* d_out, int out_size, void* d_ws, size_t ws_size,
                              hipStream_t stream) {
    const float* src = (const float*)d_in[0];
    const float* wq  = (const float*)d_in[1];
    const float* wk  = (const float*)d_in[2];
    const float* wv_ = (const float*)d_in[3];
    const float* wo  = (const float*)d_in[4];
    const float* w1  = (const float*)d_in[5];
    const float* b1  = (const float*)d_in[6];
    const float* w2  = (const float*)d_in[7];
    const float* b2  = (const float*)d_in[8];
    const float* g1  = (const float*)d_in[9];
    const float* bb1 = (const float*)d_in[10];
    const float* g2  = (const float*)d_in[11];
    const float* bb2 = (const float*)d_in[12];
    float* out = (float*)d_out;
    (void)in_sizes; (void)n_in; (void)out_size; (void)ws_size;

    char* ws = (char*)d_ws;
    size_t off = 0;
    auto alloc = [&](size_t bytes) -> char* {
        char* p = ws + off;
        off = (off + bytes + 255) & ~(size_t)255;
        return p;
    };
    float* scal = (float*)alloc(256);
    float* rowM = (float*)alloc(AROWS * 4);
    float* rowZ = (float*)alloc(AROWS * 4);
    u16* qsrc = (u16*)alloc((size_t)ROWS * KD * 2);   // later reused as qX
    u16* qwq  = (u16*)alloc((size_t)KD * KD * 2);
    u16* qwk  = (u16*)alloc((size_t)KD * KD * 2);
    u16* qwv  = (u16*)alloc((size_t)KD * KD * 2);
    u16* qwo  = (u16*)alloc((size_t)KD * KD * 2);
    u16* qw1  = (u16*)alloc((size_t)DFF * KD * 2);
    u16* qw2  = (u16*)alloc((size_t)KD * DFF * 2);
    u16* qQ   = (u16*)alloc((size_t)ROWS * KD * 2);   // later reused as qA
    u16* qK   = (u16*)alloc((size_t)ROWS * KD * 2);   // later reused as qAo
    u16* VT   = (u16*)alloc((size_t)ROWS * KD * 2);   // V codes transposed; later reused as qFF
    u16* qH   = (u16*)alloc((size_t)ROWS * DFF * 2);
    i8*  qS   = (i8*)alloc((size_t)NBATCH * NH * SEQ * SEQ);
    float* xbuf = (float*)alloc((size_t)ROWS * KD * 4);
    float* ybuf = (float*)alloc((size_t)ROWS * DFF * 4);
    u16* qX  = qsrc;
    u16* qA  = qQ;
    u16* qAo = qK;
    u16* qFF = VT;

    hipMemsetAsync(scal, 0, 256, stream);

    // 1+2. batched absmax + quant of the 7 f32 inputs (scal[0..6])
    Batch7 b7;
    b7.x[0] = (const float4*)src; b7.q[0] = (ushort4*)qsrc; b7.n4[0] = (long long)ROWS * KD / 4;
    b7.x[1] = (const float4*)wq;  b7.q[1] = (ushort4*)qwq;  b7.n4[1] = (long long)KD * KD / 4;
    b7.x[2] = (const float4*)wk;  b7.q[2] = (ushort4*)qwk;  b7.n4[2] = (long long)KD * KD / 4;
    b7.x[3] = (const float4*)wv_; b7.q[3] = (ushort4*)qwv;  b7.n4[3] = (long long)KD * KD / 4;
    b7.x[4] = (const float4*)wo;  b7.q[4] = (ushort4*)qwo;  b7.n4[4] = (long long)KD * KD / 4;
    b7.x[5] = (const float4*)w1;  b7.q[5] = (ushort4*)qw1;  b7.n4[5] = (long long)DFF * KD / 4;
    b7.x[6] = (const float4*)w2;  b7.q[6] = (ushort4*)qw2;  b7.n4[6] = (long long)KD * DFF / 4;
    absmax_multi<<<dim3(256, 7), 256, 0, stream>>>(b7, scal);
    quant_multi<<<dim3(256, 7), 256, 0, stream>>>(b7, scal);

    // 3. Q/K/V projections
    dim3 gP(KD / 128, ROWS / 128, 1);
    gemm_mfma<0><<<gP, 256, 0, stream>>>(qsrc, KD, 0, 0, qwq, KD, 0, 0, ybuf, KD, 0, 0,
                                         KD, 1, scal, 0, 1, -1, nullptr, &scal[7]);
    quant_to_bf16<<<4096, 256, 0, stream>>>((const float4*)ybuf, &scal[7], (ushort4*)qQ);
    gemm_mfma<0><<<gP, 256, 0, stream>>>(qsrc, KD, 0, 0, qwk, KD, 0, 0, ybuf, KD, 0, 0,
                                         KD, 1, scal, 0, 2, -1, nullptr, &scal[8]);
    quant_to_bf16<<<4096, 256, 0, stream>>>((const float4*)ybuf, &scal[8], (ushort4*)qK);
    gemm_mfma<0><<<gP, 256, 0, stream>>>(qsrc, KD, 0, 0, qwv, KD, 0, 0, ybuf, KD, 0, 0,
                                         KD, 1, scal, 0, 3, -1, nullptr, &scal[9]);
    quant_v_t<<<dim3(SEQ / 64, NH, NBATCH), 256, 0, stream>>>(ybuf, &scal[9], VT);

    // 4. scores: pass1 max only, pass2 quantize to int8
    dim3 gS(SEQ / 128, SEQ / 128, NBATCH * NH);
    const long long sQb = (long long)SEQ * KD;
    const long long sSb = (long long)NH * SEQ * SEQ;
    const long long sSh = (long long)SEQ * SEQ;
    gemm_mfma<1><<<gS, 256, 0, stream>>>(qQ, KD, sQb, HDIM, qK, KD, sQb, HDIM,
                                         nullptr, SEQ, sSb, sSh,
                                         HDIM, NH, scal, 7, 8, -1, nullptr, &scal[10]);
    gemm_mfma<2><<<gS, 256, 0, stream>>>(qQ, KD, sQb, HDIM, qK, KD, sQb, HDIM,
                                         qS, SEQ, sSb, sSh,
                                         HDIM, NH, scal, 7, 8, 10, nullptr, nullptr);

    // 5. softmax stats (rowM, rowZ, pmax)
    softmax_stats<<<1024, 256, 0, stream>>>(qS, scal, rowM, rowZ, &scal[11]);

    // 6. attn = fq(probs) @ fq(v)  (softmax+quant fused into A staging, VT B-staging)
    dim3 gV(1, SEQ / 128, NBATCH * NH);
    gemm_pv<<<gV, 256, 0, stream>>>(qS, VT, ybuf, rowM, rowZ, scal, &scal[12]);
    quant_to_bf16<<<4096, 256, 0, stream>>>((const float4*)ybuf, &scal[12], (ushort4*)qA);

    // 7. output projection
    gemm_mfma<0><<<gP, 256, 0, stream>>>(qA, KD, 0, 0, qwo, KD, 0, 0, ybuf, KD, 0, 0,
                                         KD, 1, scal, 12, 4, -1, nullptr, &scal[13]);
    quant_to_bf16<<<4096, 256, 0, stream>>>((const float4*)ybuf, &scal[13], (ushort4*)qAo);

    // 8. residual + LN1
    ln_res<true><<<ROWS, 256, 0, stream>>>(src, qAo, scal, 13, g1, bb1, xbuf, &scal[14]);
    quant_to_bf16<<<4096, 256, 0, stream>>>((const float4*)xbuf, &scal[14], (ushort4*)qX);

    // 9. FFN1 + quant + relu + requant
    dim3 gF1(DFF / 128, ROWS / 128, 1);
    gemm_mfma<0><<<gF1, 256, 0, stream>>>(qX, KD, 0, 0, qw1, KD, 0, 0, ybuf, DFF, 0, 0,
                                          KD, 1, scal, 14, 5, -1, b1, &scal[15]);
    relu_quant_a<<<2048, 256, 0, stream>>>((const float4*)ybuf, scal, (ushort4*)qH, &scal[16]);
    relu_quant_b<<<2048, 256, 0, stream>>>((ushort4*)qH, scal);

    // 10. FFN2
    dim3 gF2(KD / 128, ROWS / 128, 1);
    gemm_mfma<0><<<gF2, 256, 0, stream>>>(qH, DFF, 0, 0, qw2, DFF, 0, 0, ybuf, KD, 0, 0,
                                          DFF, 1, scal, 16, 6, -1, b2, &scal[17]);
    quant_to_bf16<<<4096, 256, 0, stream>>>((const float4*)ybuf, &scal[17], (ushort4*)qFF);

    // 11. residual + LN2 -> out
    ln_res<false><<<ROWS, 256, 0, stream>>>(xbuf, qFF, scal, 17, g2, bb2, out, nullptr);
}

// Round 8
// 787.066 us; speedup vs baseline: 4.8297x; 1.0835x over previous
//
#include <hip/hip_runtime.h>
#include <cstdint>

// Problem constants
constexpr int KD   = 1024;
constexpr int NH   = 16;
constexpr int HDIM = 64;
constexpr int DFF  = 4096;
constexpr int NBATCH = 4;
constexpr int SEQ  = 1024;
constexpr int ROWS = NBATCH * SEQ;                       // 4096
constexpr long long AROWS = (long long)NBATCH * NH * SEQ; // 65536

typedef signed char i8;
typedef unsigned short u16;
typedef __attribute__((ext_vector_type(8))) short short8;
typedef __attribute__((ext_vector_type(4))) float f32x4;

__device__ __forceinline__ void atomicMaxF(float* a, float v) {
    atomicMax((unsigned int*)a, __float_as_uint(v));   // valid: values >= 0, buffer zeroed
}
// int8 code values are exact in bf16: low 16 bits of their f32 pattern are zero.
__device__ __forceinline__ float c2f(u16 u) { return __uint_as_float(((unsigned)u) << 16); }
__device__ __forceinline__ u16   f2c(float f) { return (u16)(__float_as_uint(f) >> 16); }
__device__ __forceinline__ float qclamp(float x) { return fminf(fmaxf(x, -128.f), 127.f); }

#define GLDS16(gp, lp) __builtin_amdgcn_global_load_lds( \
    (const __attribute__((address_space(1))) void*)(gp), \
    (__attribute__((address_space(3))) void*)(lp), 16, 0, 0)

// ---------------- batched absmax + quant for the 7 f32 inputs ----------------
struct Batch7 {
    const float4* x[7];
    ushort4*      q[7];
    long long     n4[7];
};

__global__ __launch_bounds__(256) void absmax_multi(Batch7 b7, float* __restrict__ scal) {
    int t = blockIdx.y;
    const float4* __restrict__ x = b7.x[t];
    long long n4 = b7.n4[t];
    float m = 0.f;
    for (long long i = (long long)blockIdx.x * 256 + threadIdx.x; i < n4;
         i += (long long)gridDim.x * 256) {
        float4 v = x[i];
        m = fmaxf(m, fmaxf(fmaxf(fabsf(v.x), fabsf(v.y)), fmaxf(fabsf(v.z), fabsf(v.w))));
    }
    #pragma unroll
    for (int off = 32; off; off >>= 1) m = fmaxf(m, __shfl_xor(m, off, 64));
    __shared__ float sm[4];
    int lane = threadIdx.x & 63, wid = threadIdx.x >> 6;
    if (lane == 0) sm[wid] = m;
    __syncthreads();
    if (threadIdx.x == 0) atomicMaxF(&scal[t], fmaxf(fmaxf(sm[0], sm[1]), fmaxf(sm[2], sm[3])));
}

__global__ __launch_bounds__(256) void quant_multi(Batch7 b7, const float* __restrict__ scal) {
    int t = blockIdx.y;
    const float4* __restrict__ x = b7.x[t];
    ushort4* __restrict__ q = b7.q[t];
    long long n4 = b7.n4[t];
    float s = fmaxf(scal[t] * (1.f / 127.f), 1e-8f);
    for (long long i = (long long)blockIdx.x * 256 + threadIdx.x; i < n4;
         i += (long long)gridDim.x * 256) {
        float4 v = x[i];
        ushort4 o;
        o.x = f2c(qclamp(rintf(v.x / s)));
        o.y = f2c(qclamp(rintf(v.y / s)));
        o.z = f2c(qclamp(rintf(v.z / s)));
        o.w = f2c(qclamp(rintf(v.w / s)));
        q[i] = o;
    }
}

// ---------------- quantize f32 -> bf16 code bits (exact grid: n/1024 blocks) ----------------
__global__ __launch_bounds__(256) void quant_to_bf16(const float4* __restrict__ x,
                                                     const float* __restrict__ mp,
                                                     ushort4* __restrict__ q) {
    long long i = (long long)blockIdx.x * 256 + threadIdx.x;
    float s = fmaxf(mp[0] * (1.f / 127.f), 1e-8f);
    float4 v = x[i];
    ushort4 o;
    o.x = f2c(qclamp(rintf(v.x / s)));
    o.y = f2c(qclamp(rintf(v.y / s)));
    o.z = f2c(qclamp(rintf(v.z / s)));
    o.w = f2c(qclamp(rintf(v.w / s)));
    q[i] = o;
}

// ---------------- fused quant + transpose of V:  VT[b*16+h][d][k] = codes(V[b][k][h*64+d]) ----
__global__ __launch_bounds__(256) void quant_v_t(const float* __restrict__ y,
                                                 const float* __restrict__ mp,
                                                 u16* __restrict__ VT) {
    __shared__ u16 t[64][66];                      // +2 pad: col-read stride 33 banks == 1 mod 32
    float s = fmaxf(mp[0] * (1.f / 127.f), 1e-8f);
    int kt = blockIdx.x, h = blockIdx.y, b = blockIdx.z;
    int tid = threadIdx.x;
    int r = tid >> 2, c0 = (tid & 3) * 16;
    const float* base = y + ((long long)(b * SEQ + kt * 64 + r)) * KD + h * 64 + c0;
    #pragma unroll
    for (int v4 = 0; v4 < 4; ++v4) {
        float4 v = ((const float4*)base)[v4];
        t[r][c0 + v4 * 4 + 0] = f2c(qclamp(rintf(v.x / s)));
        t[r][c0 + v4 * 4 + 1] = f2c(qclamp(rintf(v.y / s)));
        t[r][c0 + v4 * 4 + 2] = f2c(qclamp(rintf(v.z / s)));
        t[r][c0 + v4 * 4 + 3] = f2c(qclamp(rintf(v.w / s)));
    }
    __syncthreads();
    int rr = tid >> 2, cc = (tid & 3) * 16;        // rr = d, cc = k offset
    alignas(16) u16 o[16];
    #pragma unroll
    for (int j = 0; j < 16; ++j) o[j] = t[cc + j][rr];
    u16* ob = VT + ((long long)(b * NH + h) * HDIM + rr) * SEQ + kt * 64 + cc;
    ((int4*)ob)[0] = ((int4*)o)[0];
    ((int4*)ob)[1] = ((int4*)o)[1];
}

// ---------------- MFMA GEMM on bf16 codes: C = sa*sb*(A @ B^T) (+bias) ----------------
// 128x128 tile, BK=64, 4 waves (2x2 of 64x64), global_load_lds staging (m97 structure).
// GRID: blockIdx.x = M-tile (XCD swizzle: same-x blocks share A panel within an XCD),
//       blockIdx.y = N-tile, blockIdx.z = batch/head/fusion slice.
// mstep: per-z offset applied to ib scale index and maxout slot (QKV fusion).
// MODE 0: write f32 + track max; 1: max only; 2: write int8 quantized by scal[iout].
template<int MODE>
__global__ __launch_bounds__(256) void gemm_mfma(
    const u16* __restrict__ A, int lda, long long sAb, long long sAh,
    const u16* __restrict__ B, int ldb, long long sBb, long long sBh,
    void* __restrict__ Cout, int ldc, long long sCb, long long sCh,
    int Kg, int Hdiv,
    const float* __restrict__ scal, int ia, int ib, int iout,
    const float* __restrict__ bias, float* __restrict__ maxout, int mstep)
{
    __shared__ u16 As[128][64];
    __shared__ u16 Bs[128][64];
    __shared__ float wred[4];

    int z = blockIdx.z, zb = z / Hdiv, zh = z % Hdiv;
    A += (long long)zb * sAb + (long long)zh * sAh;
    B += (long long)zb * sBb + (long long)zh * sBh;
    long long coff = (long long)zb * sCb + (long long)zh * sCh;

    int tid = threadIdx.x, lane = tid & 63, wid = tid >> 6;
    int wr = wid >> 1, wc = wid & 1;
    int m0 = blockIdx.x * 128, n0 = blockIdx.y * 128;   // m fastest -> XCD shares A panel

    f32x4 acc[4][4];
    #pragma unroll
    for (int m = 0; m < 4; ++m)
        #pragma unroll
        for (int n = 0; n < 4; ++n) acc[m][n] = (f32x4)0.0f;

    int srow = lane >> 3;            // 0..7 row within 8-row slab
    int scol = (lane & 7) * 8;       // bf16 element col (16B chunk)

    for (int k0 = 0; k0 < Kg; k0 += 64) {
        #pragma unroll
        for (int i = 0; i < 4; ++i) {
            int r = wid * 32 + i * 8 + srow;
            GLDS16(A + (long long)(m0 + r) * lda + k0 + scol, &As[wid * 32 + i * 8][0]);
        }
        #pragma unroll
        for (int i = 0; i < 4; ++i) {
            int r = wid * 32 + i * 8 + srow;
            GLDS16(B + (long long)(n0 + r) * ldb + k0 + scol, &Bs[wid * 32 + i * 8][0]);
        }
        __syncthreads();
        #pragma unroll
        for (int kk = 0; kk < 2; ++kk) {
            short8 af[4], bf[4];
            #pragma unroll
            for (int m = 0; m < 4; ++m)
                af[m] = *(const short8*)&As[wr * 64 + m * 16 + (lane & 15)][kk * 32 + (lane >> 4) * 8];
            #pragma unroll
            for (int n = 0; n < 4; ++n)
                bf[n] = *(const short8*)&Bs[wc * 64 + n * 16 + (lane & 15)][kk * 32 + (lane >> 4) * 8];
            #pragma unroll
            for (int m = 0; m < 4; ++m)
                #pragma unroll
                for (int n = 0; n < 4; ++n)
                    acc[m][n] = __builtin_amdgcn_mfma_f32_16x16x32_bf16(af[m], bf[n], acc[m][n], 0, 0, 0);
        }
        __syncthreads();
    }

    float sa = fmaxf(scal[ia] * (1.f / 127.f), 1e-8f);
    float sb = fmaxf(scal[ib + zh * mstep] * (1.f / 127.f), 1e-8f);
    float ab = sa * sb;
    float so = (MODE == 2) ? fmaxf(scal[iout] * (1.f / 127.f), 1e-8f) : 1.f;
    float lmax = 0.f;
    #pragma unroll
    for (int m = 0; m < 4; ++m)
        #pragma unroll
        for (int n = 0; n < 4; ++n)
            #pragma unroll
            for (int r = 0; r < 4; ++r) {
                int row = m0 + wr * 64 + m * 16 + (lane >> 4) * 4 + r;
                int col = n0 + wc * 64 + n * 16 + (lane & 15);
                float y = ab * acc[m][n][r];
                if (bias) y += bias[col];
                if (MODE == 0)
                    ((float*)Cout)[coff + (long long)row * ldc + col] = y;
                if (MODE == 2) {
                    float qv = qclamp(rintf(y / so));
                    ((i8*)Cout)[coff + (long long)row * ldc + col] = (i8)(int)qv;
                }
                if (MODE <= 1) lmax = fmaxf(lmax, fabsf(y));
            }
    if (MODE <= 1) {
        #pragma unroll
        for (int off = 32; off; off >>= 1) lmax = fmaxf(lmax, __shfl_xor(lmax, off, 64));
        if (lane == 0) wred[wid] = lmax;
        __syncthreads();
        if (tid == 0) atomicMaxF(maxout + zh * mstep, fmaxf(fmaxf(wred[0], wred[1]), fmaxf(wred[2], wred[3])));
    }
}

// ---------------- softmax stats: wave per row, grid-stride 16 rows/wave, exact expf ----------
__global__ __launch_bounds__(256) void softmax_stats(const i8* __restrict__ qS,
                                                     const float* __restrict__ scal,
                                                     float* __restrict__ rowM, float* __restrict__ rowZ,
                                                     float* __restrict__ pmax) {
    int lane = threadIdx.x & 63, wid = threadIdx.x >> 6;
    int gw = blockIdx.x * 4 + wid;                   // 4096 waves total
    float ss = fmaxf(scal[10] * (1.f / 127.f), 1e-8f);
    float c = ss * 0.125f;
    float lpm = 0.f;
    for (long long row = gw; row < AROWS; row += 4096) {
        union { int4 q; i8 b[16]; } u;
        u.q = *(const int4*)(qS + row * SEQ + lane * 16);
        float m = -1e30f;
        #pragma unroll
        for (int j = 0; j < 16; ++j) m = fmaxf(m, (float)u.b[j]);
        #pragma unroll
        for (int off = 32; off; off >>= 1) m = fmaxf(m, __shfl_xor(m, off, 64));
        float zz = 0.f;
        #pragma unroll
        for (int j = 0; j < 16; ++j) zz += expf(c * ((float)u.b[j] - m));
        #pragma unroll
        for (int off = 32; off; off >>= 1) zz += __shfl_xor(zz, off, 64);
        if (lane == 0) { rowM[row] = m; rowZ[row] = zz; lpm = fmaxf(lpm, 1.f / zz); }
    }
    #pragma unroll
    for (int off = 32; off; off >>= 1) lpm = fmaxf(lpm, __shfl_xor(lpm, off, 64));
    __shared__ float sm[4];
    if (lane == 0) sm[wid] = lpm;
    __syncthreads();
    if (threadIdx.x == 0) atomicMaxF(pmax, fmaxf(fmaxf(sm[0], sm[1]), fmaxf(sm[2], sm[3])));
}

// ---------------- PV GEMM: A = fq(softmax(qS)) computed in staging, B = VT (global_load_lds) ---
// GRID: blockIdx.x = z (head slice; same-head blocks share an XCD's L2 for VT),
//       blockIdx.y = 128-row M-tile. 4 waves each 32 rows.
// Math identical to passing R2/R6: pr = expf(c*(s-m))/Z ; code = rintf(pr/sp).
__global__ __launch_bounds__(256) void gemm_pv(
    const i8* __restrict__ S, const u16* __restrict__ VT, float* __restrict__ Y,
    const float* __restrict__ rowM, const float* __restrict__ rowZ,
    const float* __restrict__ scal, float* __restrict__ maxout)
{
    __shared__ u16 As[128][64];
    __shared__ u16 Bs[64][64];
    __shared__ float wred[4];

    int z = blockIdx.x, zb = z >> 4, zh = z & 15;    // head = fastest grid dim
    const i8* Sz = S + (long long)z * SEQ * SEQ;
    const u16* VTz = VT + (long long)z * HDIM * SEQ;
    float* Yz = Y + (long long)zb * SEQ * KD + zh * HDIM;
    const float* rM = rowM + (long long)z * SEQ;
    const float* rZ = rowZ + (long long)z * SEQ;

    float ss = fmaxf(scal[10] * (1.f / 127.f), 1e-8f);
    float cc = ss * 0.125f;
    float sp = fmaxf(scal[11] * (1.f / 127.f), 1e-8f);
    float sv = fmaxf(scal[9]  * (1.f / 127.f), 1e-8f);

    int tid = threadIdx.x, lane = tid & 63, wid = tid >> 6;
    int m0 = blockIdx.y * 128;

    // each thread owns one A row (two threads per row: col halves 0/32)
    int arow = tid >> 1;
    int acol = (tid & 1) * 32;
    int grow = m0 + arow;
    float mrow = rM[grow];
    float Zrow = rZ[grow];

    f32x4 acc[2][4];
    #pragma unroll
    for (int m = 0; m < 2; ++m)
        #pragma unroll
        for (int n = 0; n < 4; ++n) acc[m][n] = (f32x4)0.0f;

    int srow = lane >> 3, scol = (lane & 7) * 8;

    for (int k0 = 0; k0 < SEQ; k0 += 64) {
        // B: 64x64 VT rows via global_load_lds (2 slabs of 8 rows per wave)
        #pragma unroll
        for (int i = 0; i < 2; ++i) {
            int r = wid * 16 + i * 8;
            GLDS16(VTz + (long long)(r + srow) * SEQ + k0 + scol, &Bs[r][0]);
        }
        // A: compute 32 prob codes for this thread's row-half (exact R2 math)
        {
            union { int4 q; i8 b[16]; } u0, u1;
            const i8* sp_ = Sz + (long long)grow * SEQ + k0 + acol;
            u0.q = ((const int4*)sp_)[0];
            u1.q = ((const int4*)sp_)[1];
            alignas(16) u16 o[32];
            #pragma unroll
            for (int j = 0; j < 16; ++j) {
                float pr = expf(cc * ((float)u0.b[j] - mrow)) / Zrow;
                o[j] = f2c(qclamp(rintf(pr / sp)));
            }
            #pragma unroll
            for (int j = 0; j < 16; ++j) {
                float pr = expf(cc * ((float)u1.b[j] - mrow)) / Zrow;
                o[16 + j] = f2c(qclamp(rintf(pr / sp)));
            }
            #pragma unroll
            for (int j = 0; j < 4; ++j)
                ((int4*)&As[arow][acol])[j] = ((int4*)o)[j];
        }
        __syncthreads();
        #pragma unroll
        for (int kk = 0; kk < 2; ++kk) {
            short8 af[2], bf[4];
            #pragma unroll
            for (int m = 0; m < 2; ++m)
                af[m] = *(const short8*)&As[wid * 32 + m * 16 + (lane & 15)][kk * 32 + (lane >> 4) * 8];
            #pragma unroll
            for (int n = 0; n < 4; ++n)
                bf[n] = *(const short8*)&Bs[n * 16 + (lane & 15)][kk * 32 + (lane >> 4) * 8];
            #pragma unroll
            for (int m = 0; m < 2; ++m)
                #pragma unroll
                for (int n = 0; n < 4; ++n)
                    acc[m][n] = __builtin_amdgcn_mfma_f32_16x16x32_bf16(af[m], bf[n], acc[m][n], 0, 0, 0);
        }
        __syncthreads();
    }

    float ab = sp * sv;
    float lmax = 0.f;
    #pragma unroll
    for (int m = 0; m < 2; ++m)
        #pragma unroll
        for (int n = 0; n < 4; ++n)
            #pragma unroll
            for (int r = 0; r < 4; ++r) {
                int row = m0 + wid * 32 + m * 16 + (lane >> 4) * 4 + r;
                int col = n * 16 + (lane & 15);
                float y = ab * acc[m][n][r];
                Yz[(long long)row * KD + col] = y;
                lmax = fmaxf(lmax, fabsf(y));
            }
    #pragma unroll
    for (int off = 32; off; off >>= 1) lmax = fmaxf(lmax, __shfl_xor(lmax, off, 64));
    if (lane == 0) wred[wid] = lmax;
    __syncthreads();
    if (tid == 0) atomicMaxF(maxout, fmaxf(fmaxf(wred[0], wred[1]), fmaxf(wred[2], wred[3])));
}

// ---------------- residual + LayerNorm (one row per block, float4) ----------------
template<bool WMAX>
__global__ __launch_bounds__(256) void ln_res(const float* __restrict__ base, const u16* __restrict__ qadd,
                                              const float* __restrict__ scal, int isc,
                                              const float* __restrict__ g, const float* __restrict__ beta,
                                              float* __restrict__ out, float* __restrict__ xmax) {
    long long row = blockIdx.x;
    int tid = threadIdx.x, lane = tid & 63, wid = tid >> 6;
    float s = fmaxf(scal[isc] * (1.f / 127.f), 1e-8f);
    float4 v = ((const float4*)(base + row * KD))[tid];
    ushort4 qq = ((const ushort4*)(qadd + row * KD))[tid];
    v.x += c2f(qq.x) * s; v.y += c2f(qq.y) * s; v.z += c2f(qq.z) * s; v.w += c2f(qq.w) * s;
    float sum = v.x + v.y + v.z + v.w;
    float sq  = v.x * v.x + v.y * v.y + v.z * v.z + v.w * v.w;
    #pragma unroll
    for (int off = 32; off; off >>= 1) { sum += __shfl_xor(sum, off, 64); sq += __shfl_xor(sq, off, 64); }
    __shared__ float s1[4], s2[4];
    if (lane == 0) { s1[wid] = sum; s2[wid] = sq; }
    __syncthreads();
    sum = s1[0] + s1[1] + s1[2] + s1[3];
    sq  = s2[0] + s2[1] + s2[2] + s2[3];
    float mu  = sum * (1.f / 1024.f);
    float var = sq * (1.f / 1024.f) - mu * mu;
    float inv = 1.f / sqrtf(var + 1e-5f);
    float4 gv = ((const float4*)g)[tid];
    float4 bv = ((const float4*)beta)[tid];
    float4 o;
    o.x = (v.x - mu) * inv * gv.x + bv.x;
    o.y = (v.y - mu) * inv * gv.y + bv.y;
    o.z = (v.z - mu) * inv * gv.z + bv.z;
    o.w = (v.w - mu) * inv * gv.w + bv.w;
    ((float4*)(out + row * KD))[tid] = o;
    if (WMAX) {
        float lm = fmaxf(fmaxf(fabsf(o.x), fabsf(o.y)), fmaxf(fabsf(o.z), fabsf(o.w)));
        #pragma unroll
        for (int off = 32; off; off >>= 1) lm = fmaxf(lm, __shfl_xor(lm, off, 64));
        __syncthreads();
        if (lane == 0) s1[wid] = lm;
        __syncthreads();
        if (tid == 0) atomicMaxF(xmax, fmaxf(fmaxf(s1[0], s1[1]), fmaxf(s1[2], s1[3])));
    }
}

// ---------------- FFN mid: quantize y -> codes, track max of relu(fq(y)) ----------------
__global__ __launch_bounds__(256) void relu_quant_a(const float4* __restrict__ y,
                                                    const float* __restrict__ scal,
                                                    ushort4* __restrict__ qh, float* __restrict__ rmax) {
    constexpr long long N4 = (long long)ROWS * DFF / 4;
    float s = fmaxf(scal[15] * (1.f / 127.f), 1e-8f);
    float lm = 0.f;
    for (long long i = (long long)blockIdx.x * 256 + threadIdx.x; i < N4;
         i += (long long)gridDim.x * 256) {
        float4 v = y[i];
        float q0 = qclamp(rintf(v.x / s)), q1 = qclamp(rintf(v.y / s));
        float q2 = qclamp(rintf(v.z / s)), q3 = qclamp(rintf(v.w / s));
        ushort4 o; o.x = f2c(q0); o.y = f2c(q1); o.z = f2c(q2); o.w = f2c(q3);
        qh[i] = o;
        lm = fmaxf(lm, fmaxf(fmaxf(q0, q1), fmaxf(q2, q3)));
    }
    lm = fmaxf(lm, 0.f) * s;
    #pragma unroll
    for (int off = 32; off; off >>= 1) lm = fmaxf(lm, __shfl_xor(lm, off, 64));
    __shared__ float sm[4];
    int lane = threadIdx.x & 63, wid = threadIdx.x >> 6;
    if (lane == 0) sm[wid] = lm;
    __syncthreads();
    if (threadIdx.x == 0) atomicMaxF(rmax, fmaxf(fmaxf(sm[0], sm[1]), fmaxf(sm[2], sm[3])));
}

__global__ __launch_bounds__(256) void relu_quant_b(ushort4* __restrict__ qh,
                                                    const float* __restrict__ scal) {
    constexpr long long N4 = (long long)ROWS * DFF / 4;
    float s  = fmaxf(scal[15] * (1.f / 127.f), 1e-8f);
    float sr = fmaxf(scal[16] * (1.f / 127.f), 1e-8f);
    for (long long i = (long long)blockIdx.x * 256 + threadIdx.x; i < N4;
         i += (long long)gridDim.x * 256) {
        ushort4 q = qh[i];
        ushort4 o;
        o.x = f2c(qclamp(rintf(fmaxf(c2f(q.x), 0.f) * s / sr)));
        o.y = f2c(qclamp(rintf(fmaxf(c2f(q.y), 0.f) * s / sr)));
        o.z = f2c(qclamp(rintf(fmaxf(c2f(q.z), 0.f) * s / sr)));
        o.w = f2c(qclamp(rintf(fmaxf(c2f(q.w), 0.f) * s / sr)));
        qh[i] = o;
    }
}

// ---------------- launch ----------------
extern "C" void kernel_launch(void* const* d_in, const int* in_sizes, int n_in,
                              void* d_out, int out_size, void* d_ws, size_t ws_size,
                              hipStream_t stream) {
    const float* src = (const float*)d_in[0];
    const float* wq  = (const float*)d_in[1];
    const float* wk  = (const float*)d_in[2];
    const float* wv_ = (const float*)d_in[3];
    const float* wo  = (const float*)d_in[4];
    const float* w1  = (const float*)d_in[5];
    const float* b1  = (const float*)d_in[6];
    const float* w2  = (const float*)d_in[7];
    const float* b2  = (const float*)d_in[8];
    const float* g1  = (const float*)d_in[9];
    const float* bb1 = (const float*)d_in[10];
    const float* g2  = (const float*)d_in[11];
    const float* bb2 = (const float*)d_in[12];
    float* out = (float*)d_out;
    (void)in_sizes; (void)n_in; (void)out_size; (void)ws_size;

    char* ws = (char*)d_ws;
    size_t off = 0;
    auto alloc = [&](size_t bytes) -> char* {
        char* p = ws + off;
        off = (off + bytes + 255) & ~(size_t)255;
        return p;
    };
    float* scal = (float*)alloc(256);
    float* rowM = (float*)alloc(AROWS * 4);
    float* rowZ = (float*)alloc(AROWS * 4);
    u16* qsrc = (u16*)alloc((size_t)ROWS * KD * 2);   // later reused as qX
    u16* qwq  = (u16*)alloc((size_t)KD * KD * 2);     // qwq/qwk/qwv contiguous (2MB each, 256B-aligned)
    u16* qwk  = (u16*)alloc((size_t)KD * KD * 2);
    u16* qwv  = (u16*)alloc((size_t)KD * KD * 2);
    u16* qwo  = (u16*)alloc((size_t)KD * KD * 2);
    u16* qw1  = (u16*)alloc((size_t)DFF * KD * 2);
    u16* qw2  = (u16*)alloc((size_t)KD * DFF * 2);
    u16* qQ   = (u16*)alloc((size_t)ROWS * KD * 2);   // later reused as qA
    u16* qK   = (u16*)alloc((size_t)ROWS * KD * 2);   // later reused as qAo
    u16* VT   = (u16*)alloc((size_t)ROWS * KD * 2);   // V codes transposed; later reused as qFF
    u16* qH   = (u16*)alloc((size_t)ROWS * DFF * 2);
    i8*  qS   = (i8*)alloc((size_t)NBATCH * NH * SEQ * SEQ);
    float* xbuf = (float*)alloc((size_t)ROWS * KD * 4);
    float* ybuf = (float*)alloc((size_t)ROWS * DFF * 4);   // holds 4x 16MB f32 slabs
    u16* qX  = qsrc;
    u16* qA  = qQ;
    u16* qAo = qK;
    u16* qFF = VT;

    hipMemsetAsync(scal, 0, 256, stream);

    // 1+2. batched absmax + quant of the 7 f32 inputs (scal[0..6])
    Batch7 b7;
    b7.x[0] = (const float4*)src; b7.q[0] = (ushort4*)qsrc; b7.n4[0] = (long long)ROWS * KD / 4;
    b7.x[1] = (const float4*)wq;  b7.q[1] = (ushort4*)qwq;  b7.n4[1] = (long long)KD * KD / 4;
    b7.x[2] = (const float4*)wk;  b7.q[2] = (ushort4*)qwk;  b7.n4[2] = (long long)KD * KD / 4;
    b7.x[3] = (const float4*)wv_; b7.q[3] = (ushort4*)qwv;  b7.n4[3] = (long long)KD * KD / 4;
    b7.x[4] = (const float4*)wo;  b7.q[4] = (ushort4*)qwo;  b7.n4[4] = (long long)KD * KD / 4;
    b7.x[5] = (const float4*)w1;  b7.q[5] = (ushort4*)qw1;  b7.n4[5] = (long long)DFF * KD / 4;
    b7.x[6] = (const float4*)w2;  b7.q[6] = (ushort4*)qw2;  b7.n4[6] = (long long)KD * DFF / 4;
    absmax_multi<<<dim3(256, 7), 256, 0, stream>>>(b7, scal);
    quant_multi<<<dim3(256, 7), 256, 0, stream>>>(b7, scal);

    const long long NKD = (long long)ROWS * KD;

    // 3. Q/K/V projections FUSED: z=0/1/2 selects weight (contiguous), ybuf slab, scal[7+z]
    dim3 gQKV(ROWS / 128, KD / 128, 3);
    gemm_mfma<0><<<gQKV, 256, 0, stream>>>(qsrc, KD, 0, 0,
                                           qwq, KD, 0, (long long)KD * KD,
                                           ybuf, KD, 0, NKD,
                                           KD, 3, scal, 0, 1, -1, nullptr, &scal[7], 1);
    quant_to_bf16<<<4096, 256, 0, stream>>>((const float4*)ybuf, &scal[7], (ushort4*)qQ);
    quant_to_bf16<<<4096, 256, 0, stream>>>((const float4*)(ybuf + NKD), &scal[8], (ushort4*)qK);
    quant_v_t<<<dim3(SEQ / 64, NH, NBATCH), 256, 0, stream>>>(ybuf + 2 * NKD, &scal[9], VT);

    // 4. scores: pass1 max only, pass2 quantize to int8
    dim3 gS(SEQ / 128, SEQ / 128, NBATCH * NH);
    const long long sQb = (long long)SEQ * KD;
    const long long sSb = (long long)NH * SEQ * SEQ;
    const long long sSh = (long long)SEQ * SEQ;
    gemm_mfma<1><<<gS, 256, 0, stream>>>(qQ, KD, sQb, HDIM, qK, KD, sQb, HDIM,
                                         nullptr, SEQ, sSb, sSh,
                                         HDIM, NH, scal, 7, 8, -1, nullptr, &scal[10], 0);
    gemm_mfma<2><<<gS, 256, 0, stream>>>(qQ, KD, sQb, HDIM, qK, KD, sQb, HDIM,
                                         qS, SEQ, sSb, sSh,
                                         HDIM, NH, scal, 7, 8, 10, nullptr, nullptr, 0);

    // 5. softmax stats (rowM, rowZ, pmax)
    softmax_stats<<<1024, 256, 0, stream>>>(qS, scal, rowM, rowZ, &scal[11]);

    // 6. attn = fq(probs) @ fq(v)  (head = fastest grid dim for per-XCD VT reuse)
    dim3 gV(NBATCH * NH, SEQ / 128);
    gemm_pv<<<gV, 256, 0, stream>>>(qS, VT, ybuf, rowM, rowZ, scal, &scal[12]);
    quant_to_bf16<<<4096, 256, 0, stream>>>((const float4*)ybuf, &scal[12], (ushort4*)qA);

    // 7. output projection
    dim3 gP(ROWS / 128, KD / 128, 1);
    gemm_mfma<0><<<gP, 256, 0, stream>>>(qA, KD, 0, 0, qwo, KD, 0, 0, ybuf, KD, 0, 0,
                                         KD, 1, scal, 12, 4, -1, nullptr, &scal[13], 0);
    quant_to_bf16<<<4096, 256, 0, stream>>>((const float4*)ybuf, &scal[13], (ushort4*)qAo);

    // 8. residual + LN1
    ln_res<true><<<ROWS, 256, 0, stream>>>(src, qAo, scal, 13, g1, bb1, xbuf, &scal[14]);
    quant_to_bf16<<<4096, 256, 0, stream>>>((const float4*)xbuf, &scal[14], (ushort4*)qX);

    // 9. FFN1 + quant + relu + requant
    dim3 gF1(ROWS / 128, DFF / 128, 1);
    gemm_mfma<0><<<gF1, 256, 0, stream>>>(qX, KD, 0, 0, qw1, KD, 0, 0, ybuf, DFF, 0, 0,
                                          KD, 1, scal, 14, 5, -1, b1, &scal[15], 0);
    relu_quant_a<<<2048, 256, 0, stream>>>((const float4*)ybuf, scal, (ushort4*)qH, &scal[16]);
    relu_quant_b<<<2048, 256, 0, stream>>>((ushort4*)qH, scal);

    // 10. FFN2
    dim3 gF2(ROWS / 128, KD / 128, 1);
    gemm_mfma<0><<<gF2, 256, 0, stream>>>(qH, DFF, 0, 0, qw2, DFF, 0, 0, ybuf, KD, 0, 0,
                                          DFF, 1, scal, 16, 6, -1, b2, &scal[17], 0);
    quant_to_bf16<<<4096, 256, 0, stream>>>((const float4*)ybuf, &scal[17], (ushort4*)qFF);

    // 11. residual + LN2 -> out
    ln_res<false><<<ROWS, 256, 0, stream>>>(xbuf, qFF, scal, 17, g2, bb2, out, nullptr);
}

// Round 11
// 740.883 us; speedup vs baseline: 5.1308x; 1.0623x over previous
//
#include <hip/hip_runtime.h>
#include <cstdint>

// Problem constants
constexpr int KD   = 1024;
constexpr int NH   = 16;
constexpr int HDIM = 64;
constexpr int DFF  = 4096;
constexpr int NBATCH = 4;
constexpr int SEQ  = 1024;
constexpr int ROWS = NBATCH * SEQ;                       // 4096
constexpr long long AROWS = (long long)NBATCH * NH * SEQ; // 65536

typedef signed char i8;
typedef unsigned short u16;
typedef __attribute__((ext_vector_type(8))) short short8;
typedef __attribute__((ext_vector_type(4))) float f32x4;

__device__ __forceinline__ void atomicMaxF(float* a, float v) {
    atomicMax((unsigned int*)a, __float_as_uint(v));   // valid: values >= 0, buffer zeroed
}
// int8 code values are exact in bf16: low 16 bits of their f32 pattern are zero.
__device__ __forceinline__ float c2f(u16 u) { return __uint_as_float(((unsigned)u) << 16); }
__device__ __forceinline__ u16   f2c(float f) { return (u16)(__float_as_uint(f) >> 16); }
__device__ __forceinline__ float qclamp(float x) { return fminf(fmaxf(x, -128.f), 127.f); }

#define GLDS16(gp, lp) __builtin_amdgcn_global_load_lds( \
    (const __attribute__((address_space(1))) void*)(gp), \
    (__attribute__((address_space(3))) void*)(lp), 16, 0, 0)

// ---------------- batched absmax + quant for the 7 f32 inputs ----------------
struct Batch7 {
    const float4* x[7];
    ushort4*      q[7];
    long long     n4[7];
};

__global__ __launch_bounds__(256) void absmax_multi(Batch7 b7, float* __restrict__ scal) {
    int t = blockIdx.y;
    const float4* __restrict__ x = b7.x[t];
    long long n4 = b7.n4[t];
    float m = 0.f;
    for (long long i = (long long)blockIdx.x * 256 + threadIdx.x; i < n4;
         i += (long long)gridDim.x * 256) {
        float4 v = x[i];
        m = fmaxf(m, fmaxf(fmaxf(fabsf(v.x), fabsf(v.y)), fmaxf(fabsf(v.z), fabsf(v.w))));
    }
    #pragma unroll
    for (int off = 32; off; off >>= 1) m = fmaxf(m, __shfl_xor(m, off, 64));
    __shared__ float sm[4];
    int lane = threadIdx.x & 63, wid = threadIdx.x >> 6;
    if (lane == 0) sm[wid] = m;
    __syncthreads();
    if (threadIdx.x == 0) atomicMaxF(&scal[t], fmaxf(fmaxf(sm[0], sm[1]), fmaxf(sm[2], sm[3])));
}

__global__ __launch_bounds__(256) void quant_multi(Batch7 b7, const float* __restrict__ scal) {
    int t = blockIdx.y;
    const float4* __restrict__ x = b7.x[t];
    ushort4* __restrict__ q = b7.q[t];
    long long n4 = b7.n4[t];
    float s = fmaxf(scal[t] * (1.f / 127.f), 1e-8f);
    for (long long i = (long long)blockIdx.x * 256 + threadIdx.x; i < n4;
         i += (long long)gridDim.x * 256) {
        float4 v = x[i];
        ushort4 o;
        o.x = f2c(qclamp(rintf(v.x / s)));
        o.y = f2c(qclamp(rintf(v.y / s)));
        o.z = f2c(qclamp(rintf(v.z / s)));
        o.w = f2c(qclamp(rintf(v.w / s)));
        q[i] = o;
    }
}

// ---------------- quantize f32 -> bf16 code bits (exact grid: n/1024 blocks) ----------------
__global__ __launch_bounds__(256) void quant_to_bf16(const float4* __restrict__ x,
                                                     const float* __restrict__ mp,
                                                     ushort4* __restrict__ q) {
    long long i = (long long)blockIdx.x * 256 + threadIdx.x;
    float s = fmaxf(mp[0] * (1.f / 127.f), 1e-8f);
    float4 v = x[i];
    ushort4 o;
    o.x = f2c(qclamp(rintf(v.x / s)));
    o.y = f2c(qclamp(rintf(v.y / s)));
    o.z = f2c(qclamp(rintf(v.z / s)));
    o.w = f2c(qclamp(rintf(v.w / s)));
    q[i] = o;
}

// ---------------- fused quant + transpose of V:  VT[b*16+h][d][k] = codes(V[b][k][h*64+d]) ----
__global__ __launch_bounds__(256) void quant_v_t(const float* __restrict__ y,
                                                 const float* __restrict__ mp,
                                                 u16* __restrict__ VT) {
    __shared__ u16 t[64][66];                      // +2 pad: col-read stride 33 banks == 1 mod 32
    float s = fmaxf(mp[0] * (1.f / 127.f), 1e-8f);
    int kt = blockIdx.x, h = blockIdx.y, b = blockIdx.z;
    int tid = threadIdx.x;
    int r = tid >> 2, c0 = (tid & 3) * 16;
    const float* base = y + ((long long)(b * SEQ + kt * 64 + r)) * KD + h * 64 + c0;
    #pragma unroll
    for (int v4 = 0; v4 < 4; ++v4) {
        float4 v = ((const float4*)base)[v4];
        t[r][c0 + v4 * 4 + 0] = f2c(qclamp(rintf(v.x / s)));
        t[r][c0 + v4 * 4 + 1] = f2c(qclamp(rintf(v.y / s)));
        t[r][c0 + v4 * 4 + 2] = f2c(qclamp(rintf(v.z / s)));
        t[r][c0 + v4 * 4 + 3] = f2c(qclamp(rintf(v.w / s)));
    }
    __syncthreads();
    int rr = tid >> 2, cc = (tid & 3) * 16;        // rr = d, cc = k offset
    alignas(16) u16 o[16];
    #pragma unroll
    for (int j = 0; j < 16; ++j) o[j] = t[cc + j][rr];
    u16* ob = VT + ((long long)(b * NH + h) * HDIM + rr) * SEQ + kt * 64 + cc;
    ((int4*)ob)[0] = ((int4*)o)[0];
    ((int4*)ob)[1] = ((int4*)o)[1];
}

// ---------------- MFMA GEMM on bf16 codes: C = sa*sb*(A @ B^T) (+bias) ----------------
// 128xBN tile, BK=64, 4 waves (2x2; wave tile 64 x BN/2), global_load_lds staging.
// BN=128 for wide-N GEMMs; BN=64 doubles the grid for N=1024/K-heavy cases (occupancy).
// GRID: blockIdx.x = M-tile (m fastest -> co-XCD blocks share the A panel),
//       blockIdx.y = N-tile, blockIdx.z = batch/head/fusion slice.
// mstep: per-z offset on ib scale index and maxout slot (QKV fusion).
// MODE 0: write f32 + track max; 1: max only; 2: write int8 quantized by scal[iout].
template<int MODE, int BN>
__global__ __launch_bounds__(256) void gemm_mfma(
    const u16* __restrict__ A, int lda, long long sAb, long long sAh,
    const u16* __restrict__ B, int ldb, long long sBb, long long sBh,
    void* __restrict__ Cout, int ldc, long long sCb, long long sCh,
    int Kg, int Hdiv,
    const float* __restrict__ scal, int ia, int ib, int iout,
    const float* __restrict__ bias, float* __restrict__ maxout, int mstep)
{
    constexpr int NW = BN / 32;       // n-fragments per wave (wave tile 64 x BN/2)
    __shared__ u16 As[128][64];
    __shared__ u16 Bs[BN][64];
    __shared__ float wred[4];

    int z = blockIdx.z, zb = z / Hdiv, zh = z % Hdiv;
    A += (long long)zb * sAb + (long long)zh * sAh;
    B += (long long)zb * sBb + (long long)zh * sBh;
    long long coff = (long long)zb * sCb + (long long)zh * sCh;

    int tid = threadIdx.x, lane = tid & 63, wid = tid >> 6;
    int wr = wid >> 1, wc = wid & 1;
    int m0 = blockIdx.x * 128, n0 = blockIdx.y * BN;

    f32x4 acc[4][NW];
    #pragma unroll
    for (int m = 0; m < 4; ++m)
        #pragma unroll
        for (int n = 0; n < NW; ++n) acc[m][n] = (f32x4)0.0f;

    int srow = lane >> 3;            // 0..7 row within 8-row slab
    int scol = (lane & 7) * 8;       // bf16 element col (16B chunk)

    for (int k0 = 0; k0 < Kg; k0 += 64) {
        #pragma unroll
        for (int i = 0; i < 4; ++i) {
            int r = wid * 32 + i * 8;                 // wave stride 32 = 128/4 rows
            GLDS16(A + (long long)(m0 + r + srow) * lda + k0 + scol, &As[r][0]);
        }
        #pragma unroll
        for (int i = 0; i < BN / 32; ++i) {
            int r = wid * (BN / 4) + i * 8;           // FIXED: wave stride BN/4 (was BN/8)
            GLDS16(B + (long long)(n0 + r + srow) * ldb + k0 + scol, &Bs[r][0]);
        }
        __syncthreads();
        #pragma unroll
        for (int kk = 0; kk < 2; ++kk) {
            short8 af[4], bf[NW];
            #pragma unroll
            for (int m = 0; m < 4; ++m)
                af[m] = *(const short8*)&As[wr * 64 + m * 16 + (lane & 15)][kk * 32 + (lane >> 4) * 8];
            #pragma unroll
            for (int n = 0; n < NW; ++n)
                bf[n] = *(const short8*)&Bs[wc * (BN / 2) + n * 16 + (lane & 15)][kk * 32 + (lane >> 4) * 8];
            #pragma unroll
            for (int m = 0; m < 4; ++m)
                #pragma unroll
                for (int n = 0; n < NW; ++n)
                    acc[m][n] = __builtin_amdgcn_mfma_f32_16x16x32_bf16(af[m], bf[n], acc[m][n], 0, 0, 0);
        }
        __syncthreads();
    }

    float sa = fmaxf(scal[ia] * (1.f / 127.f), 1e-8f);
    float sb = fmaxf(scal[ib + zh * mstep] * (1.f / 127.f), 1e-8f);
    float ab = sa * sb;
    float so = (MODE == 2) ? fmaxf(scal[iout] * (1.f / 127.f), 1e-8f) : 1.f;
    float lmax = 0.f;
    #pragma unroll
    for (int m = 0; m < 4; ++m)
        #pragma unroll
        for (int n = 0; n < NW; ++n)
            #pragma unroll
            for (int r = 0; r < 4; ++r) {
                int row = m0 + wr * 64 + m * 16 + (lane >> 4) * 4 + r;
                int col = n0 + wc * (BN / 2) + n * 16 + (lane & 15);
                float y = ab * acc[m][n][r];
                if (bias) y += bias[col];
                if (MODE == 0)
                    ((float*)Cout)[coff + (long long)row * ldc + col] = y;
                if (MODE == 2) {
                    float qv = qclamp(rintf(y / so));
                    ((i8*)Cout)[coff + (long long)row * ldc + col] = (i8)(int)qv;
                }
                if (MODE <= 1) lmax = fmaxf(lmax, fabsf(y));
            }
    if (MODE <= 1) {
        #pragma unroll
        for (int off = 32; off; off >>= 1) lmax = fmaxf(lmax, __shfl_xor(lmax, off, 64));
        if (lane == 0) wred[wid] = lmax;
        __syncthreads();
        if (tid == 0) atomicMaxF(maxout + zh * mstep, fmaxf(fmaxf(wred[0], wred[1]), fmaxf(wred[2], wred[3])));
    }
}

// ---------------- softmax stats: wave per row, grid-stride 16 rows/wave, fast exp ----------
__global__ __launch_bounds__(256) void softmax_stats(const i8* __restrict__ qS,
                                                     const float* __restrict__ scal,
                                                     float* __restrict__ rowM, float* __restrict__ rowZ,
                                                     float* __restrict__ pmax) {
    int lane = threadIdx.x & 63, wid = threadIdx.x >> 6;
    int gw = blockIdx.x * 4 + wid;                   // 4096 waves total
    float ss = fmaxf(scal[10] * (1.f / 127.f), 1e-8f);
    float c = ss * 0.125f;
    float lpm = 0.f;
    for (long long row = gw; row < AROWS; row += 4096) {
        union { int4 q; i8 b[16]; } u;
        u.q = *(const int4*)(qS + row * SEQ + lane * 16);
        float m = -1e30f;
        #pragma unroll
        for (int j = 0; j < 16; ++j) m = fmaxf(m, (float)u.b[j]);
        #pragma unroll
        for (int off = 32; off; off >>= 1) m = fmaxf(m, __shfl_xor(m, off, 64));
        float zz = 0.f;
        #pragma unroll
        for (int j = 0; j < 16; ++j) zz += __expf(c * ((float)u.b[j] - m));
        #pragma unroll
        for (int off = 32; off; off >>= 1) zz += __shfl_xor(zz, off, 64);
        if (lane == 0) { rowM[row] = m; rowZ[row] = zz; lpm = fmaxf(lpm, 1.f / zz); }
    }
    #pragma unroll
    for (int off = 32; off; off >>= 1) lpm = fmaxf(lpm, __shfl_xor(lpm, off, 64));
    __shared__ float sm[4];
    if (lane == 0) sm[wid] = lpm;
    __syncthreads();
    if (threadIdx.x == 0) atomicMaxF(pmax, fmaxf(fmaxf(sm[0], sm[1]), fmaxf(sm[2], sm[3])));
}

// ---------------- PV GEMM: A = fq(softmax(qS)) computed in staging, B = VT (global_load_lds) ---
// GRID: blockIdx.x = z (head slice; same-head blocks share an XCD's L2 for VT),
//       blockIdx.y = 128-row M-tile. 4 waves each 32 rows.
// Fast exp (__expf = v_exp_f32); /Z and /sp divisions kept exact.
__global__ __launch_bounds__(256) void gemm_pv(
    const i8* __restrict__ S, const u16* __restrict__ VT, float* __restrict__ Y,
    const float* __restrict__ rowM, const float* __restrict__ rowZ,
    const float* __restrict__ scal, float* __restrict__ maxout)
{
    __shared__ u16 As[128][64];
    __shared__ u16 Bs[64][64];
    __shared__ float wred[4];

    int z = blockIdx.x, zb = z >> 4, zh = z & 15;    // head = fastest grid dim
    const i8* Sz = S + (long long)z * SEQ * SEQ;
    const u16* VTz = VT + (long long)z * HDIM * SEQ;
    float* Yz = Y + (long long)zb * SEQ * KD + zh * HDIM;
    const float* rM = rowM + (long long)z * SEQ;
    const float* rZ = rowZ + (long long)z * SEQ;

    float ss = fmaxf(scal[10] * (1.f / 127.f), 1e-8f);
    float cc = ss * 0.125f;
    float sp = fmaxf(scal[11] * (1.f / 127.f), 1e-8f);
    float sv = fmaxf(scal[9]  * (1.f / 127.f), 1e-8f);

    int tid = threadIdx.x, lane = tid & 63, wid = tid >> 6;
    int m0 = blockIdx.y * 128;

    // each thread owns one A row (two threads per row: col halves 0/32)
    int arow = tid >> 1;
    int acol = (tid & 1) * 32;
    int grow = m0 + arow;
    float mrow = rM[grow];
    float Zrow = rZ[grow];

    f32x4 acc[2][4];
    #pragma unroll
    for (int m = 0; m < 2; ++m)
        #pragma unroll
        for (int n = 0; n < 4; ++n) acc[m][n] = (f32x4)0.0f;

    int srow = lane >> 3, scol = (lane & 7) * 8;

    for (int k0 = 0; k0 < SEQ; k0 += 64) {
        // B: 64x64 VT rows via global_load_lds (2 slabs of 8 rows per wave)
        #pragma unroll
        for (int i = 0; i < 2; ++i) {
            int r = wid * 16 + i * 8;
            GLDS16(VTz + (long long)(r + srow) * SEQ + k0 + scol, &Bs[r][0]);
        }
        // A: compute 32 prob codes for this thread's row-half
        {
            union { int4 q; i8 b[16]; } u0, u1;
            const i8* sp_ = Sz + (long long)grow * SEQ + k0 + acol;
            u0.q = ((const int4*)sp_)[0];
            u1.q = ((const int4*)sp_)[1];
            alignas(16) u16 o[32];
            #pragma unroll
            for (int j = 0; j < 16; ++j) {
                float pr = __expf(cc * ((float)u0.b[j] - mrow)) / Zrow;
                o[j] = f2c(qclamp(rintf(pr / sp)));
            }
            #pragma unroll
            for (int j = 0; j < 16; ++j) {
                float pr = __expf(cc * ((float)u1.b[j] - mrow)) / Zrow;
                o[16 + j] = f2c(qclamp(rintf(pr / sp)));
            }
            #pragma unroll
            for (int j = 0; j < 4; ++j)
                ((int4*)&As[arow][acol])[j] = ((int4*)o)[j];
        }
        __syncthreads();
        #pragma unroll
        for (int kk = 0; kk < 2; ++kk) {
            short8 af[2], bf[4];
            #pragma unroll
            for (int m = 0; m < 2; ++m)
                af[m] = *(const short8*)&As[wid * 32 + m * 16 + (lane & 15)][kk * 32 + (lane >> 4) * 8];
            #pragma unroll
            for (int n = 0; n < 4; ++n)
                bf[n] = *(const short8*)&Bs[n * 16 + (lane & 15)][kk * 32 + (lane >> 4) * 8];
            #pragma unroll
            for (int m = 0; m < 2; ++m)
                #pragma unroll
                for (int n = 0; n < 4; ++n)
                    acc[m][n] = __builtin_amdgcn_mfma_f32_16x16x32_bf16(af[m], bf[n], acc[m][n], 0, 0, 0);
        }
        __syncthreads();
    }

    float ab = sp * sv;
    float lmax = 0.f;
    #pragma unroll
    for (int m = 0; m < 2; ++m)
        #pragma unroll
        for (int n = 0; n < 4; ++n)
            #pragma unroll
            for (int r = 0; r < 4; ++r) {
                int row = m0 + wid * 32 + m * 16 + (lane >> 4) * 4 + r;
                int col = n * 16 + (lane & 15);
                float y = ab * acc[m][n][r];
                Yz[(long long)row * KD + col] = y;
                lmax = fmaxf(lmax, fabsf(y));
            }
    #pragma unroll
    for (int off = 32; off; off >>= 1) lmax = fmaxf(lmax, __shfl_xor(lmax, off, 64));
    if (lane == 0) wred[wid] = lmax;
    __syncthreads();
    if (tid == 0) atomicMaxF(maxout, fmaxf(fmaxf(wred[0], wred[1]), fmaxf(wred[2], wred[3])));
}

// ---------------- residual + LayerNorm (one row per block, float4) ----------------
template<bool WMAX>
__global__ __launch_bounds__(256) void ln_res(const float* __restrict__ base, const u16* __restrict__ qadd,
                                              const float* __restrict__ scal, int isc,
                                              const float* __restrict__ g, const float* __restrict__ beta,
                                              float* __restrict__ out, float* __restrict__ xmax) {
    long long row = blockIdx.x;
    int tid = threadIdx.x, lane = tid & 63, wid = tid >> 6;
    float s = fmaxf(scal[isc] * (1.f / 127.f), 1e-8f);
    float4 v = ((const float4*)(base + row * KD))[tid];
    ushort4 qq = ((const ushort4*)(qadd + row * KD))[tid];
    v.x += c2f(qq.x) * s; v.y += c2f(qq.y) * s; v.z += c2f(qq.z) * s; v.w += c2f(qq.w) * s;
    float sum = v.x + v.y + v.z + v.w;
    float sq  = v.x * v.x + v.y * v.y + v.z * v.z + v.w * v.w;
    #pragma unroll
    for (int off = 32; off; off >>= 1) { sum += __shfl_xor(sum, off, 64); sq += __shfl_xor(sq, off, 64); }
    __shared__ float s1[4], s2[4];
    if (lane == 0) { s1[wid] = sum; s2[wid] = sq; }
    __syncthreads();
    sum = s1[0] + s1[1] + s1[2] + s1[3];
    sq  = s2[0] + s2[1] + s2[2] + s2[3];
    float mu  = sum * (1.f / 1024.f);
    float var = sq * (1.f / 1024.f) - mu * mu;
    float inv = 1.f / sqrtf(var + 1e-5f);
    float4 gv = ((const float4*)g)[tid];
    float4 bv = ((const float4*)beta)[tid];
    float4 o;
    o.x = (v.x - mu) * inv * gv.x + bv.x;
    o.y = (v.y - mu) * inv * gv.y + bv.y;
    o.z = (v.z - mu) * inv * gv.z + bv.z;
    o.w = (v.w - mu) * inv * gv.w + bv.w;
    ((float4*)(out + row * KD))[tid] = o;
    if (WMAX) {
        float lm = fmaxf(fmaxf(fabsf(o.x), fabsf(o.y)), fmaxf(fabsf(o.z), fabsf(o.w)));
        #pragma unroll
        for (int off = 32; off; off >>= 1) lm = fmaxf(lm, __shfl_xor(lm, off, 64));
        __syncthreads();
        if (lane == 0) s1[wid] = lm;
        __syncthreads();
        if (tid == 0) atomicMaxF(xmax, fmaxf(fmaxf(s1[0], s1[1]), fmaxf(s1[2], s1[3])));
    }
}

// ---------------- FFN mid: quantize y -> codes, track max of relu(fq(y)) ----------------
__global__ __launch_bounds__(256) void relu_quant_a(const float4* __restrict__ y,
                                                    const float* __restrict__ scal,
                                                    ushort4* __restrict__ qh, float* __restrict__ rmax) {
    constexpr long long N4 = (long long)ROWS * DFF / 4;
    float s = fmaxf(scal[15] * (1.f / 127.f), 1e-8f);
    float lm = 0.f;
    for (long long i = (long long)blockIdx.x * 256 + threadIdx.x; i < N4;
         i += (long long)gridDim.x * 256) {
        float4 v = y[i];
        float q0 = qclamp(rintf(v.x / s)), q1 = qclamp(rintf(v.y / s));
        float q2 = qclamp(rintf(v.z / s)), q3 = qclamp(rintf(v.w / s));
        ushort4 o; o.x = f2c(q0); o.y = f2c(q1); o.z = f2c(q2); o.w = f2c(q3);
        qh[i] = o;
        lm = fmaxf(lm, fmaxf(fmaxf(q0, q1), fmaxf(q2, q3)));
    }
    lm = fmaxf(lm, 0.f) * s;
    #pragma unroll
    for (int off = 32; off; off >>= 1) lm = fmaxf(lm, __shfl_xor(lm, off, 64));
    __shared__ float sm[4];
    int lane = threadIdx.x & 63, wid = threadIdx.x >> 6;
    if (lane == 0) sm[wid] = lm;
    __syncthreads();
    if (threadIdx.x == 0) atomicMaxF(rmax, fmaxf(fmaxf(sm[0], sm[1]), fmaxf(sm[2], sm[3])));
}

__global__ __launch_bounds__(256) void relu_quant_b(ushort4* __restrict__ qh,
                                                    const float* __restrict__ scal) {
    constexpr long long N4 = (long long)ROWS * DFF / 4;
    float s  = fmaxf(scal[15] * (1.f / 127.f), 1e-8f);
    float sr = fmaxf(scal[16] * (1.f / 127.f), 1e-8f);
    for (long long i = (long long)blockIdx.x * 256 + threadIdx.x; i < N4;
         i += (long long)gridDim.x * 256) {
        ushort4 q = qh[i];
        ushort4 o;
        o.x = f2c(qclamp(rintf(fmaxf(c2f(q.x), 0.f) * s / sr)));
        o.y = f2c(qclamp(rintf(fmaxf(c2f(q.y), 0.f) * s / sr)));
        o.z = f2c(qclamp(rintf(fmaxf(c2f(q.z), 0.f) * s / sr)));
        o.w = f2c(qclamp(rintf(fmaxf(c2f(q.w), 0.f) * s / sr)));
        qh[i] = o;
    }
}

// ---------------- launch ----------------
extern "C" void kernel_launch(void* const* d_in, const int* in_sizes, int n_in,
                              void* d_out, int out_size, void* d_ws, size_t ws_size,
                              hipStream_t stream) {
    const float* src = (const float*)d_in[0];
    const float* wq  = (const float*)d_in[1];
    const float* wk  = (const float*)d_in[2];
    const float* wv_ = (const float*)d_in[3];
    const float* wo  = (const float*)d_in[4];
    const float* w1  = (const float*)d_in[5];
    const float* b1  = (const float*)d_in[6];
    const float* w2  = (const float*)d_in[7];
    const float* b2  = (const float*)d_in[8];
    const float* g1  = (const float*)d_in[9];
    const float* bb1 = (const float*)d_in[10];
    const float* g2  = (const float*)d_in[11];
    const float* bb2 = (const float*)d_in[12];
    float* out = (float*)d_out;
    (void)in_sizes; (void)n_in; (void)out_size; (void)ws_size;

    char* ws = (char*)d_ws;
    size_t off = 0;
    auto alloc = [&](size_t bytes) -> char* {
        char* p = ws + off;
        off = (off + bytes + 255) & ~(size_t)255;
        return p;
    };
    float* scal = (float*)alloc(256);
    float* rowM = (float*)alloc(AROWS * 4);
    float* rowZ = (float*)alloc(AROWS * 4);
    u16* qsrc = (u16*)alloc((size_t)ROWS * KD * 2);   // later reused as qX
    u16* qwq  = (u16*)alloc((size_t)KD * KD * 2);     // qwq/qwk/qwv contiguous (2MB each, 256B-aligned)
    u16* qwk  = (u16*)alloc((size_t)KD * KD * 2);
    u16* qwv  = (u16*)alloc((size_t)KD * KD * 2);
    u16* qwo  = (u16*)alloc((size_t)KD * KD * 2);
    u16* qw1  = (u16*)alloc((size_t)DFF * KD * 2);
    u16* qw2  = (u16*)alloc((size_t)KD * DFF * 2);
    u16* qQ   = (u16*)alloc((size_t)ROWS * KD * 2);   // later reused as qA
    u16* qK   = (u16*)alloc((size_t)ROWS * KD * 2);   // later reused as qAo
    u16* VT   = (u16*)alloc((size_t)ROWS * KD * 2);   // V codes transposed; later reused as qFF
    u16* qH   = (u16*)alloc((size_t)ROWS * DFF * 2);
    i8*  qS   = (i8*)alloc((size_t)NBATCH * NH * SEQ * SEQ);
    float* xbuf = (float*)alloc((size_t)ROWS * KD * 4);
    float* ybuf = (float*)alloc((size_t)ROWS * DFF * 4);   // holds 4x 16MB f32 slabs
    u16* qX  = qsrc;
    u16* qA  = qQ;
    u16* qAo = qK;
    u16* qFF = VT;

    hipMemsetAsync(scal, 0, 256, stream);

    // 1+2. batched absmax + quant of the 7 f32 inputs (scal[0..6])
    Batch7 b7;
    b7.x[0] = (const float4*)src; b7.q[0] = (ushort4*)qsrc; b7.n4[0] = (long long)ROWS * KD / 4;
    b7.x[1] = (const float4*)wq;  b7.q[1] = (ushort4*)qwq;  b7.n4[1] = (long long)KD * KD / 4;
    b7.x[2] = (const float4*)wk;  b7.q[2] = (ushort4*)qwk;  b7.n4[2] = (long long)KD * KD / 4;
    b7.x[3] = (const float4*)wv_; b7.q[3] = (ushort4*)qwv;  b7.n4[3] = (long long)KD * KD / 4;
    b7.x[4] = (const float4*)wo;  b7.q[4] = (ushort4*)qwo;  b7.n4[4] = (long long)KD * KD / 4;
    b7.x[5] = (const float4*)w1;  b7.q[5] = (ushort4*)qw1;  b7.n4[5] = (long long)DFF * KD / 4;
    b7.x[6] = (const float4*)w2;  b7.q[6] = (ushort4*)qw2;  b7.n4[6] = (long long)KD * DFF / 4;
    absmax_multi<<<dim3(256, 7), 256, 0, stream>>>(b7, scal);
    quant_multi<<<dim3(256, 7), 256, 0, stream>>>(b7, scal);

    const long long NKD = (long long)ROWS * KD;

    // 3. Q/K/V projections FUSED: z=0/1/2 selects weight (contiguous), ybuf slab, scal[7+z]
    dim3 gQKV(ROWS / 128, KD / 128, 3);
    gemm_mfma<0, 128><<<gQKV, 256, 0, stream>>>(qsrc, KD, 0, 0,
                                                qwq, KD, 0, (long long)KD * KD,
                                                ybuf, KD, 0, NKD,
                                                KD, 3, scal, 0, 1, -1, nullptr, &scal[7], 1);
    quant_to_bf16<<<4096, 256, 0, stream>>>((const float4*)ybuf, &scal[7], (ushort4*)qQ);
    quant_to_bf16<<<4096, 256, 0, stream>>>((const float4*)(ybuf + NKD), &scal[8], (ushort4*)qK);
    quant_v_t<<<dim3(SEQ / 64, NH, NBATCH), 256, 0, stream>>>(ybuf + 2 * NKD, &scal[9], VT);

    // 4. scores: pass1 max only, pass2 quantize to int8
    dim3 gS(SEQ / 128, SEQ / 128, NBATCH * NH);
    const long long sQb = (long long)SEQ * KD;
    const long long sSb = (long long)NH * SEQ * SEQ;
    const long long sSh = (long long)SEQ * SEQ;
    gemm_mfma<1, 128><<<gS, 256, 0, stream>>>(qQ, KD, sQb, HDIM, qK, KD, sQb, HDIM,
                                              nullptr, SEQ, sSb, sSh,
                                              HDIM, NH, scal, 7, 8, -1, nullptr, &scal[10], 0);
    gemm_mfma<2, 128><<<gS, 256, 0, stream>>>(qQ, KD, sQb, HDIM, qK, KD, sQb, HDIM,
                                              qS, SEQ, sSb, sSh,
                                              HDIM, NH, scal, 7, 8, 10, nullptr, nullptr, 0);

    // 5. softmax stats (rowM, rowZ, pmax)
    softmax_stats<<<1024, 256, 0, stream>>>(qS, scal, rowM, rowZ, &scal[11]);

    // 6. attn = fq(probs) @ fq(v)  (head = fastest grid dim for per-XCD VT reuse)
    dim3 gV(NBATCH * NH, SEQ / 128);
    gemm_pv<<<gV, 256, 0, stream>>>(qS, VT, ybuf, rowM, rowZ, scal, &scal[12]);
    quant_to_bf16<<<4096, 256, 0, stream>>>((const float4*)ybuf, &scal[12], (ushort4*)qA);

    // 7. output projection (BN=64: 512 blocks -> 2+/CU)
    dim3 gP(ROWS / 128, KD / 64, 1);
    gemm_mfma<0, 64><<<gP, 256, 0, stream>>>(qA, KD, 0, 0, qwo, KD, 0, 0, ybuf, KD, 0, 0,
                                             KD, 1, scal, 12, 4, -1, nullptr, &scal[13], 0);
    quant_to_bf16<<<4096, 256, 0, stream>>>((const float4*)ybuf, &scal[13], (ushort4*)qAo);

    // 8. residual + LN1
    ln_res<true><<<ROWS, 256, 0, stream>>>(src, qAo, scal, 13, g1, bb1, xbuf, &scal[14]);
    quant_to_bf16<<<4096, 256, 0, stream>>>((const float4*)xbuf, &scal[14], (ushort4*)qX);

    // 9. FFN1 + quant + relu + requant
    dim3 gF1(ROWS / 128, DFF / 128, 1);
    gemm_mfma<0, 128><<<gF1, 256, 0, stream>>>(qX, KD, 0, 0, qw1, KD, 0, 0, ybuf, DFF, 0, 0,
                                               KD, 1, scal, 14, 5, -1, b1, &scal[15], 0);
    relu_quant_a<<<2048, 256, 0, stream>>>((const float4*)ybuf, scal, (ushort4*)qH, &scal[16]);
    relu_quant_b<<<2048, 256, 0, stream>>>((ushort4*)qH, scal);

    // 10. FFN2 (BN=64: 512 blocks -> 2+/CU on the K=4096 GEMM)
    dim3 gF2(ROWS / 128, KD / 64, 1);
    gemm_mfma<0, 64><<<gF2, 256, 0, stream>>>(qH, DFF, 0, 0, qw2, DFF, 0, 0, ybuf, KD, 0, 0,
                                              DFF, 1, scal, 16, 6, -1, b2, &scal[17], 0);
    quant_to_bf16<<<4096, 256, 0, stream>>>((const float4*)ybuf, &scal[17], (ushort4*)qFF);

    // 11. residual + LN2 -> out
    ln_res<false><<<ROWS, 256, 0, stream>>>(xbuf, qFF, scal, 17, g2, bb2, out, nullptr);
}